// Round 14
// baseline (363.826 us; speedup 1.0000x reference)
//
#include <hip/hip_runtime.h>
#include <hip/hip_bf16.h>
#include <stdint.h>

#define BATCH 32
#define SEQ   4096
#define EMB   512
#define HEADS 8
#define HD    64
#define SCALE 0.125f   // 1/sqrt(64)

typedef __attribute__((ext_vector_type(8))) short bf16x8;
typedef __attribute__((ext_vector_type(4))) float f32x4;

__device__ __forceinline__ unsigned short f2bf(float f) {
    union { float f; unsigned int u; } v; v.f = f;
    unsigned int u = v.u;
    return (unsigned short)((u + 0x7FFFu + ((u >> 16) & 1u)) >> 16);
}
__device__ __forceinline__ float bf2f(unsigned short h) {
    union { unsigned int u; float f; } v; v.u = ((unsigned int)h) << 16;
    return v.f;
}
// HW packed fp32->bf16 (RNE): first arg -> bits[15:0], second -> bits[31:16]
__device__ __forceinline__ unsigned int cvtpk(float lo, float hi) {
    unsigned int r;
    asm("v_cvt_pk_bf16_f32 %0, %1, %2" : "=v"(r) : "v"(lo), "v"(hi));
    return r;
}
__device__ __forceinline__ float lo_as_f(unsigned int p) {
    union { unsigned int u; float f; } v; v.u = p << 16; return v.f;
}
__device__ __forceinline__ float hi_as_f(unsigned int p) {
    union { unsigned int u; float f; } v; v.u = p & 0xFFFF0000u; return v.f;
}

#define MFMA16(a, b, c) __builtin_amdgcn_mfma_f32_16x16x32_bf16((a), (b), (c), 0, 0, 0)

union F4 { float4 v; float f[4]; };
struct Regs { F4 a0, a1, a2, a3; };

// ---------------------------------------------------------------------------
// K1: P[c][b] = x_b[chunk c]^T x_b[chunk c] (fp32), svp[c][b] = chunk column
// sums (diag tiles), xbf = bf16(x) (diag tiles, XBF).
// TILE 256x256, 1024 thr / 16 waves. NCHUNK=2 -> grid 256 = 1/CU. (Round 8.)
// ---------------------------------------------------------------------------
template <int NCHUNK, bool XBF>
__global__ __launch_bounds__(1024) void k1_gram(const float* __restrict__ x,
                                                float* __restrict__ P,
                                                float* __restrict__ svp,
                                                unsigned short* __restrict__ xbf) {
  constexpr int KC  = SEQ / NCHUNK;
  constexpr int NIT = KC / 32;
  constexpr int NWG = BATCH * 4 * NCHUNK;
  constexpr int PER = NWG / 8;
  const int bid = blockIdx.x;
  const int wk  = (bid & 7) * PER + (bid >> 3);
  const int c   = (NCHUNK == 2) ? (wk & 1) : 0;
  const int tt  = (NCHUNK == 2) ? ((wk >> 1) & 3) : (wk & 3);
  const int b   = (NCHUNK == 2) ? (wk >> 3) : (wk >> 2);
  const int mt = (tt >> 1) & 1, nt = tt & 1;
  const int m0 = mt * 256, n0 = nt * 256;
  const bool diag = (mt == nt);
  const float* __restrict__ xb = x + (size_t)b * SEQ * EMB;
  const int kbeg = c * KC;

  __shared__ unsigned short L[2][64 * 148];   // [A/B], 37888 B
  __shared__ float SR[256][8];                // 8192 B

  const int tid  = threadIdx.x;
  const int lane = tid & 63;
  const int wave = tid >> 6;        // 0..15
  const int wr = (wave >> 2) * 64;
  const int wc = (wave & 3) * 64;
  const int er  = lane & 15;
  const int kb8 = (lane >> 4) * 8;

  const int fg   = lane;            // e-group: e = fg*4 + i  (256 cols)
  const int kgrp = wave >> 1;       // 0..7 -> k = kgrp*4 + j
  const bool isB = (wave & 1);
  const int pcol = isB ? n0 : m0;
  const bool active = (!diag) || (!isB);

  f32x4 acc[4][4];
#pragma unroll
  for (int i = 0; i < 4; ++i)
#pragma unroll
    for (int j = 0; j < 4; ++j) acc[i][j] = (f32x4){0.f, 0.f, 0.f, 0.f};

  float sacc[4] = {0.f, 0.f, 0.f, 0.f};

  Regs r0;

  auto loadreg = [&](int t) {
    const float* p = &xb[(size_t)(kbeg + t * 32 + kgrp * 4) * EMB + pcol + fg * 4];
    r0.a0.v = *(const float4*)p;
    r0.a1.v = *(const float4*)(p + EMB);
    r0.a2.v = *(const float4*)(p + 2 * EMB);
    r0.a3.v = *(const float4*)(p + 3 * EMB);
  };

  auto stage = [&](int t) {
    unsigned short* __restrict__ Ld = &L[isB ? 1 : 0][0];
#pragma unroll
    for (int i = 0; i < 4; ++i) {
      uint2 w;
      w.x = cvtpk(r0.a0.f[i], r0.a1.f[i]);
      w.y = cvtpk(r0.a2.f[i], r0.a3.f[i]);
      *(uint2*)&Ld[fg * 148 + i * 36 + kgrp * 4] = w;
    }
    if (diag) {
#pragma unroll
      for (int i = 0; i < 4; ++i)
        sacc[i] += (r0.a0.f[i] + r0.a1.f[i]) + (r0.a2.f[i] + r0.a3.f[i]);
      if (XBF) {
        unsigned short* xp = &xbf[((size_t)b * SEQ + kbeg + t * 32 + kgrp * 4) * EMB + m0 + fg * 4];
        uint2 xr;
        xr.x = cvtpk(r0.a0.f[0], r0.a0.f[1]); xr.y = cvtpk(r0.a0.f[2], r0.a0.f[3]);
        *(uint2*)&xp[0] = xr;
        xr.x = cvtpk(r0.a1.f[0], r0.a1.f[1]); xr.y = cvtpk(r0.a1.f[2], r0.a1.f[3]);
        *(uint2*)&xp[EMB] = xr;
        xr.x = cvtpk(r0.a2.f[0], r0.a2.f[1]); xr.y = cvtpk(r0.a2.f[2], r0.a2.f[3]);
        *(uint2*)&xp[2 * EMB] = xr;
        xr.x = cvtpk(r0.a3.f[0], r0.a3.f[1]); xr.y = cvtpk(r0.a3.f[2], r0.a3.f[3]);
        *(uint2*)&xp[3 * EMB] = xr;
      }
    }
  };

  auto frag = [&](const unsigned short* __restrict__ Ls, int e) -> bf16x8 {
    const int off = (e >> 2) * 148 + (e & 3) * 36 + kb8;
    union { bf16x8 v; uint2 u[2]; } r;
    r.u[0] = *(const uint2*)&Ls[off];
    r.u[1] = *(const uint2*)&Ls[off + 4];
    return r.v;
  };

  if (active) loadreg(0);

  for (int it = 0; it < NIT; ++it) {
    __syncthreads();                 // previous compute's LDS reads done
    if (active) stage(it);
    __syncthreads();                 // LDS tile ready
    if (active && (it + 1 < NIT)) loadreg(it + 1);   // issue early

    const unsigned short* __restrict__ LAs = &L[0][0];
    const unsigned short* __restrict__ LBs = diag ? LAs : &L[1][0];
    bf16x8 bfr[4];
#pragma unroll
    for (int ns = 0; ns < 4; ++ns) bfr[ns] = frag(LBs, wc + ns * 16 + er);
    {
      bf16x8 a0f = frag(LAs, wr + er);
      bf16x8 a1f = frag(LAs, wr + 16 + er);
#pragma unroll
      for (int ns = 0; ns < 4; ++ns) {
        acc[0][ns] = MFMA16(a0f, bfr[ns], acc[0][ns]);
        acc[1][ns] = MFMA16(a1f, bfr[ns], acc[1][ns]);
      }
    }
    {
      bf16x8 a2f = frag(LAs, wr + 32 + er);
      bf16x8 a3f = frag(LAs, wr + 48 + er);
#pragma unroll
      for (int ns = 0; ns < 4; ++ns) {
        acc[2][ns] = MFMA16(a2f, bfr[ns], acc[2][ns]);
        acc[3][ns] = MFMA16(a3f, bfr[ns], acc[3][ns]);
      }
    }
  }

  float* __restrict__ Pc = P + (size_t)(c * BATCH + b) * EMB * EMB;
#pragma unroll
  for (int ms = 0; ms < 4; ++ms)
#pragma unroll
    for (int ns = 0; ns < 4; ++ns)
#pragma unroll
      for (int r = 0; r < 4; ++r) {
        const int row = m0 + wr + ms * 16 + ((lane >> 4) * 4) + r;
        const int col = n0 + wc + ns * 16 + (lane & 15);
        Pc[(size_t)row * EMB + col] = acc[ms][ns][r];
      }

  if (diag) {
    __syncthreads();
    if (!isB) {
#pragma unroll
      for (int i = 0; i < 4; ++i) SR[fg * 4 + i][kgrp] = sacc[i];
    }
    __syncthreads();
    if (tid < 256) {
      float v = 0.f;
#pragma unroll
      for (int j = 0; j < 8; ++j) v += SR[tid][j];
      svp[(size_t)(c * BATCH + b) * EMB + m0 + tid] = v;
    }
  }
}

// ---------------------------------------------------------------------------
// K2a: A[b] = Wq @ G_b, G_b = P0_b (+ P1_b if TWO). 128^2 tile, 256 thr,
// register prefetch (round-13 proven).
// ---------------------------------------------------------------------------
template <bool TWO>
__global__ __launch_bounds__(256) void k2a_wqg(const float* __restrict__ Wq,
                                               const float* __restrict__ P,
                                               float* __restrict__ A) {
  const int bid = blockIdx.x;                 // nwg = 512
  const int wk  = (bid & 7) * 64 + (bid >> 3);
  const int b  = wk >> 4;
  const int mt = (wk >> 2) & 3;
  const int nt = wk & 3;
  const int m0 = mt * 128, n0 = nt * 128;
  const float* __restrict__ P0b = P + (size_t)b * EMB * EMB;
  const float* __restrict__ P1b = P + (size_t)(BATCH + b) * EMB * EMB;

  __shared__ unsigned short LA[128][40];
  __shared__ unsigned short LBhi[128][40];
  __shared__ unsigned short LBlo[128][40];

  const int tid  = threadIdx.x;
  const int lane = tid & 63;
  const int wave = tid >> 6;
  const int wr = (wave >> 1) * 64;
  const int wc = (wave & 1) * 64;

  f32x4 acc[4][4];
#pragma unroll
  for (int i = 0; i < 4; ++i)
#pragma unroll
    for (int j = 0; j < 4; ++j) acc[i][j] = (f32x4){0.f, 0.f, 0.f, 0.f};

  const int rA = tid >> 3, fgA = tid & 7;

  F4 ra[4], rb0[4], rb1[4];

  auto loadreg = [&](int k0) {
#pragma unroll
    for (int it = 0; it < 4; ++it) {
      const int r = rA + it * 32;
      ra[it].v  = *(const float4*)&Wq[(size_t)(m0 + r) * EMB + k0 + fgA * 4];
      rb0[it].v = *(const float4*)&P0b[(size_t)(n0 + r) * EMB + k0 + fgA * 4];
      if (TWO)
        rb1[it].v = *(const float4*)&P1b[(size_t)(n0 + r) * EMB + k0 + fgA * 4];
    }
  };

  auto stage = [&]() {
#pragma unroll
    for (int it = 0; it < 4; ++it) {
      const int r = rA + it * 32;
      uint2 u; u.x = cvtpk(ra[it].f[0], ra[it].f[1]); u.y = cvtpk(ra[it].f[2], ra[it].f[3]);
      *(uint2*)&LA[r][fgA * 4] = u;
      float v0 = rb0[it].f[0], v1 = rb0[it].f[1], v2 = rb0[it].f[2], v3 = rb0[it].f[3];
      if (TWO) { v0 += rb1[it].f[0]; v1 += rb1[it].f[1]; v2 += rb1[it].f[2]; v3 += rb1[it].f[3]; }
      uint2 h; h.x = cvtpk(v0, v1); h.y = cvtpk(v2, v3);
      uint2 l;
      l.x = cvtpk(v0 - lo_as_f(h.x), v1 - hi_as_f(h.x));
      l.y = cvtpk(v2 - lo_as_f(h.y), v3 - hi_as_f(h.y));
      *(uint2*)&LBhi[r][fgA * 4] = h;
      *(uint2*)&LBlo[r][fgA * 4] = l;
    }
  };

  loadreg(0);

  for (int k0 = 0; k0 < EMB; k0 += 32) {
    __syncthreads();
    stage();
    __syncthreads();
    if (k0 + 32 < EMB) loadreg(k0 + 32);   // issue early

    bf16x8 af[4], bh[4], bl[4];
#pragma unroll
    for (int ms = 0; ms < 4; ++ms)
      af[ms] = *(const bf16x8*)&LA[wr + ms*16 + (lane & 15)][(lane >> 4) * 8];
#pragma unroll
    for (int ns = 0; ns < 4; ++ns) {
      bh[ns] = *(const bf16x8*)&LBhi[wc + ns*16 + (lane & 15)][(lane >> 4) * 8];
      bl[ns] = *(const bf16x8*)&LBlo[wc + ns*16 + (lane & 15)][(lane >> 4) * 8];
    }
#pragma unroll
    for (int ms = 0; ms < 4; ++ms)
#pragma unroll
      for (int ns = 0; ns < 4; ++ns) {
        acc[ms][ns] = MFMA16(af[ms], bh[ns], acc[ms][ns]);
        acc[ms][ns] = MFMA16(af[ms], bl[ns], acc[ms][ns]);
      }
  }

  float* __restrict__ Ab = A + (size_t)b * EMB * EMB;
#pragma unroll
  for (int ms = 0; ms < 4; ++ms)
#pragma unroll
    for (int ns = 0; ns < 4; ++ns)
#pragma unroll
      for (int r = 0; r < 4; ++r) {
        const int row = m0 + wr + ms*16 + ((lane >> 4) * 4) + r;
        const int col = n0 + wc + ns*16 + (lane & 15);
        Ab[(size_t)row * EMB + col] = acc[ms][ns][r];
      }
}

// ---------------------------------------------------------------------------
// K2B3A (FUSED): per (b,h), 512 thr / 8 waves, grid 256.
// Waves 0-3: logits = A_h @ Wk_h^T (+bias, *1/8) -> softmax -> attn^T in LDS.
// Waves 4-7 (during the logits K-loop): compute U/W dot products, then stage
// Wo rows 0..255 (cols h*64..) into LDS (overlaps logits compute for free).
// Then all 8 waves: 2 passes of C[p*256..p*256+255, h*64..] = Wo_chunk @ attnT.
// attn never touches global; k3a launch eliminated.
// ---------------------------------------------------------------------------
template <int NCHUNK>
__global__ __launch_bounds__(512) void k2b3a(const float* __restrict__ A,
                                             const float* __restrict__ Wq,
                                             const float* __restrict__ Wk,
                                             const float* __restrict__ bq,
                                             const float* __restrict__ bk,
                                             const float* __restrict__ Wo,
                                             const float* __restrict__ svp,
                                             unsigned short* __restrict__ C) {
  const int blk = blockIdx.x;      // 256: b*8 + h
  const int b = blk >> 3;
  const int h = blk & 7;
  const float* __restrict__ Ab = A + (size_t)b * EMB * EMB + (size_t)h * HD * EMB;

  __shared__ unsigned short LAhi[64][40];   // 5120 B
  __shared__ unsigned short LAlo[64][40];   // 5120 B
  __shared__ unsigned short LB[64][40];     // 5120 B
  __shared__ float U[HD], W[HD];            // 512 B
  __shared__ unsigned short LBT[64][72];    // attn^T [kp][q], 9216 B
  __shared__ unsigned short LWO[256][72];   // Wo chunk, 36864 B   (total ~62 KB)

  const int tid  = threadIdx.x;
  const int lane = tid & 63;
  const int wave = tid >> 6;       // 0..7
  const bool qkw = (wave < 4);

  const int r8 = tid >> 3, fg8 = tid & 7;     // valid for tid < 256

  F4 va[2], vw[2];

  auto loadreg = [&](int k0) {
#pragma unroll
    for (int it = 0; it < 2; ++it) {
      const int r = r8 + it * 32;
      va[it].v = *(const float4*)&Ab[(size_t)r * EMB + k0 + fg8 * 4];
      vw[it].v = *(const float4*)&Wk[(size_t)(h*HD + r) * EMB + k0 + fg8 * 4];
    }
  };

  auto stage = [&]() {
#pragma unroll
    for (int it = 0; it < 2; ++it) {
      const int r = r8 + it * 32;
      uint2 h2; h2.x = cvtpk(va[it].f[0], va[it].f[1]); h2.y = cvtpk(va[it].f[2], va[it].f[3]);
      uint2 l2;
      l2.x = cvtpk(va[it].f[0] - lo_as_f(h2.x), va[it].f[1] - hi_as_f(h2.x));
      l2.y = cvtpk(va[it].f[2] - lo_as_f(h2.y), va[it].f[3] - hi_as_f(h2.y));
      *(uint2*)&LAhi[r][fg8*4] = h2;
      *(uint2*)&LAlo[r][fg8*4] = l2;
      uint2 ub; ub.x = cvtpk(vw[it].f[0], vw[it].f[1]); ub.y = cvtpk(vw[it].f[2], vw[it].f[3]);
      *(uint2*)&LB[r][fg8*4] = ub;
    }
  };

  if (qkw) loadreg(0);

  // waves 4-7: U = Wq_h @ s, W = Wk_h @ s (s = sum of chunk partials)
  if (!qkw) {
    const int t2 = tid - 256;
    if (t2 < 128) {
      const int q = t2 & 63;
      const float* __restrict__ wrow = (t2 < 64 ? Wq : Wk) + (size_t)(h * HD + q) * EMB;
      float a = 0.f;
      for (int i = 0; i < EMB; i += 4) {
        const float4 wv = *(const float4*)&wrow[i];
        float4 sv = *(const float4*)&svp[(size_t)b * EMB + i];
        if (NCHUNK == 2) {
          const float4 s1 = *(const float4*)&svp[(size_t)(BATCH + b) * EMB + i];
          sv.x += s1.x; sv.y += s1.y; sv.z += s1.z; sv.w += s1.w;
        }
        a += wv.x*sv.x + wv.y*sv.y + wv.z*sv.z + wv.w*sv.w;
      }
      if (t2 < 64) U[q] = a; else W[q] = a;
    }
  }

  f32x4 acc[4];
#pragma unroll
  for (int i = 0; i < 4; ++i) acc[i] = (f32x4){0.f, 0.f, 0.f, 0.f};

  for (int k0 = 0; k0 < EMB; k0 += 32) {
    __syncthreads();
    if (qkw) {
      stage();
    } else {
      // stage Wo rows (k0/32)*16 .. +15 of column block h (overlaps logits)
      const int t2 = tid - 256;
      const int row = (k0 >> 5) * 16 + (t2 >> 4);
      const int fg = t2 & 15;
      const float4 v = *(const float4*)&Wo[(size_t)row * EMB + h*HD + fg * 4];
      uint2 u; u.x = cvtpk(v.x, v.y); u.y = cvtpk(v.z, v.w);
      *(uint2*)&LWO[row][fg * 4] = u;
    }
    __syncthreads();
    if (qkw) {
      if (k0 + 32 < EMB) loadreg(k0 + 32);   // issue early

      const bf16x8 ah = *(const bf16x8*)&LAhi[wave*16 + (lane & 15)][(lane >> 4) * 8];
      const bf16x8 al = *(const bf16x8*)&LAlo[wave*16 + (lane & 15)][(lane >> 4) * 8];
#pragma unroll
      for (int ns = 0; ns < 4; ++ns) {
        const bf16x8 bb = *(const bf16x8*)&LB[ns*16 + (lane & 15)][(lane >> 4) * 8];
        acc[ns] = MFMA16(ah, bb, acc[ns]);
        acc[ns] = MFMA16(al, bb, acc[ns]);
      }
    }
  }

  // softmax epilogue (waves 0-3), write attn^T to LDS
  if (qkw) {
    const int colb = lane & 15;
    float bkv[4], wv_[4];
#pragma unroll
    for (int ns = 0; ns < 4; ++ns) {
      bkv[ns] = bk[h*HD + ns*16 + colb];
      wv_[ns] = W[ns*16 + colb];
    }
#pragma unroll
    for (int r = 0; r < 4; ++r) {
      const int row = wave*16 + ((lane >> 4) * 4) + r;
      const float bqv = bq[h*HD + row];
      const float uv  = U[row];
      float vals[4];
#pragma unroll
      for (int ns = 0; ns < 4; ++ns)
        vals[ns] = (acc[ns][r] + uv * bkv[ns] + bqv * wv_[ns] + 4096.f * bqv * bkv[ns]) * SCALE;
      float mx = fmaxf(fmaxf(vals[0], vals[1]), fmaxf(vals[2], vals[3]));
#pragma unroll
      for (int m = 1; m < 16; m <<= 1) mx = fmaxf(mx, __shfl_xor(mx, m));
      float sum = 0.f;
#pragma unroll
      for (int ns = 0; ns < 4; ++ns) { vals[ns] = expf(vals[ns] - mx); sum += vals[ns]; }
#pragma unroll
      for (int m = 1; m < 16; m <<= 1) sum += __shfl_xor(sum, m);
      const float inv = 1.f / sum;
#pragma unroll
      for (int ns = 0; ns < 4; ++ns)
        LBT[ns*16 + colb][row] = f2bf(vals[ns] * inv);
    }
  }
  __syncthreads();   // LBT + LWO(pass 0) ready

  // phase 2: C[p*256 + 0..255, h*64..h*64+63] = Wo_chunk @ attnT, 2 passes
  unsigned short* __restrict__ Cb = C + (size_t)b * EMB * EMB;
  for (int p = 0; p < 2; ++p) {
    if (p == 1) {
      __syncthreads();   // pass-0 LWO reads done
      // restage LWO with Wo rows 256..511 (all 512 threads)
      const int rr = tid >> 4;        // 0..31
      const int fg = tid & 15;
#pragma unroll
      for (int j = 0; j < 8; ++j) {
        const int row = rr + j * 32;
        const float4 v = *(const float4*)&Wo[(size_t)(256 + row) * EMB + h*HD + fg * 4];
        uint2 u; u.x = cvtpk(v.x, v.y); u.y = cvtpk(v.z, v.w);
        *(uint2*)&LWO[row][fg * 4] = u;
      }
      __syncthreads();
    }

    f32x4 acc2[2][4];
#pragma unroll
    for (int i = 0; i < 2; ++i)
#pragma unroll
      for (int j = 0; j < 4; ++j) acc2[i][j] = (f32x4){0.f, 0.f, 0.f, 0.f};

#pragma unroll
    for (int kk = 0; kk < 2; ++kk) {
      bf16x8 af[2], bfr[4];
#pragma unroll
      for (int ms = 0; ms < 2; ++ms)
        af[ms] = *(const bf16x8*)&LWO[wave*32 + ms*16 + (lane & 15)][kk*32 + (lane >> 4) * 8];
#pragma unroll
      for (int ns = 0; ns < 4; ++ns)
        bfr[ns] = *(const bf16x8*)&LBT[ns*16 + (lane & 15)][kk*32 + (lane >> 4) * 8];
#pragma unroll
      for (int ms = 0; ms < 2; ++ms)
#pragma unroll
        for (int ns = 0; ns < 4; ++ns)
          acc2[ms][ns] = MFMA16(af[ms], bfr[ns], acc2[ms][ns]);
    }

#pragma unroll
    for (int ms = 0; ms < 2; ++ms)
#pragma unroll
      for (int ns = 0; ns < 4; ++ns)
#pragma unroll
        for (int r = 0; r < 4; ++r) {
          const int row = p*256 + wave*32 + ms*16 + ((lane >> 4) * 4) + r;
          const int col = h*HD + ns*16 + (lane & 15);
          Cb[(size_t)row * EMB + col] = f2bf(acc2[ms][ns][r]);
        }
  }
}

// ---------------------------------------------------------------------------
// K3b: D[b] = C_b @ Wv (bf16 out) + FUSED e[b] = C_b @ bv + bo.
// Register prefetch (round-13). grid 32*16, block 256.
// ---------------------------------------------------------------------------
__global__ __launch_bounds__(256) void k3b_d(const unsigned short* __restrict__ C,
                                             const float* __restrict__ Wv,
                                             const float* __restrict__ bv,
                                             const float* __restrict__ bo,
                                             unsigned short* __restrict__ D,
                                             float* __restrict__ evec) {
  const int bid = blockIdx.x;                 // nwg = 512
  const int wk  = (bid & 7) * 64 + (bid >> 3);
  const int b  = wk >> 4;
  const int mt = (wk >> 2) & 3;
  const int nt = wk & 3;
  const int m0 = mt * 128, n0 = nt * 128;
  const unsigned short* __restrict__ Cb = C + (size_t)b * EMB * EMB;

  __shared__ unsigned short LA[128][40];
  __shared__ unsigned short LB[32 * 148];     // [n-subblocked][k] transposed Wv
  __shared__ float BV[EMB];

  const int tid  = threadIdx.x;
  const int lane = tid & 63;
  const int wave = tid >> 6;
  const int wr = (wave >> 1) * 64;
  const int wc = (wave & 1) * 64;
  const int er  = lane & 15;
  const int kb8 = (lane >> 4) * 8;

  const bool doE = (nt == 0);
  if (doE) {
    BV[tid] = bv[tid];
    BV[tid + 256] = bv[tid + 256];
  }

  f32x4 acc[4][4];
#pragma unroll
  for (int i = 0; i < 4; ++i)
#pragma unroll
    for (int j = 0; j < 4; ++j) acc[i][j] = (f32x4){0.f, 0.f, 0.f, 0.f};

  float eacc[4] = {0.f, 0.f, 0.f, 0.f};

  const int rA = tid >> 3, fgA = tid & 7;
  const int fgB = tid & 31;    // n-group: n = fgB*4 + i
  const int kgB = tid >> 5;    // k = kgB*4 + j

  ushort4 rc[4];
  F4 rb0, rb1, rb2, rb3;

  auto loadreg = [&](int k0) {
#pragma unroll
    for (int it = 0; it < 4; ++it) {
      const int r = rA + it * 32;
      rc[it] = *(const ushort4*)&Cb[(size_t)(m0 + r) * EMB + k0 + fgA * 4];
    }
    const float* p = &Wv[(size_t)(k0 + kgB * 4) * EMB + n0 + fgB * 4];
    rb0.v = *(const float4*)p;
    rb1.v = *(const float4*)(p + EMB);
    rb2.v = *(const float4*)(p + 2 * EMB);
    rb3.v = *(const float4*)(p + 3 * EMB);
  };

  auto stage = [&](int k0) {
    float bvr[4];
    if (doE) {
#pragma unroll
      for (int j = 0; j < 4; ++j) bvr[j] = BV[k0 + fgA * 4 + j];
    }
#pragma unroll
    for (int it = 0; it < 4; ++it) {
      const int r = rA + it * 32;
      *(ushort4*)&LA[r][fgA*4] = rc[it];
      if (doE)
        eacc[it] += bf2f(rc[it].x)*bvr[0] + bf2f(rc[it].y)*bvr[1]
                  + bf2f(rc[it].z)*bvr[2] + bf2f(rc[it].w)*bvr[3];
    }
#pragma unroll
    for (int i = 0; i < 4; ++i) {
      uint2 w;
      w.x = cvtpk(rb0.f[i], rb1.f[i]);
      w.y = cvtpk(rb2.f[i], rb3.f[i]);
      *(uint2*)&LB[fgB * 148 + i * 36 + kgB * 4] = w;
    }
  };

  loadreg(0);

  for (int k0 = 0; k0 < EMB; k0 += 32) {
    __syncthreads();
    stage(k0);
    __syncthreads();
    if (k0 + 32 < EMB) loadreg(k0 + 32);   // issue early

    bf16x8 af[4], bfr[4];
#pragma unroll
    for (int ms = 0; ms < 4; ++ms)
      af[ms] = *(const bf16x8*)&LA[wr + ms*16 + er][kb8];
#pragma unroll
    for (int ns = 0; ns < 4; ++ns) {
      const int e = wc + ns * 16 + er;
      const int off = (e >> 2) * 148 + (e & 3) * 36 + kb8;
      union { bf16x8 v; uint2 u[2]; } r;
      r.u[0] = *(const uint2*)&LB[off];
      r.u[1] = *(const uint2*)&LB[off + 4];
      bfr[ns] = r.v;
    }
#pragma unroll
    for (int ms = 0; ms < 4; ++ms)
#pragma unroll
      for (int ns = 0; ns < 4; ++ns)
        acc[ms][ns] = MFMA16(af[ms], bfr[ns], acc[ms][ns]);
  }

  unsigned short* __restrict__ Db = D + (size_t)b * EMB * EMB;
#pragma unroll
  for (int ms = 0; ms < 4; ++ms)
#pragma unroll
    for (int ns = 0; ns < 4; ++ns)
#pragma unroll
      for (int r = 0; r < 4; ++r) {
        const int row = m0 + wr + ms*16 + ((lane >> 4) * 4) + r;
        const int col = n0 + wc + ns*16 + (lane & 15);
        Db[(size_t)row * EMB + col] = f2bf(acc[ms][ns][r]);
      }

  if (doE) {
#pragma unroll
    for (int it = 0; it < 4; ++it) {
#pragma unroll
      for (int m = 1; m < 8; m <<= 1) eacc[it] += __shfl_xor(eacc[it], m);
      if (fgA == 0) {
        const int row = m0 + rA + it * 32;
        evec[b * EMB + row] = eacc[it] + bo[row];
      }
    }
  }
}

// ---------------------------------------------------------------------------
// K4: out[b] = x_b @ D_b^T + e_b. TILE 128x512, 1024 thr / 16 waves.
// grid 1024. NONTEMPORAL out stores (268 MB streamed, never re-read):
// avoids write-allocate pollution of L2/LLC where xbf lives.
// ---------------------------------------------------------------------------
template <bool XBF>
__global__ __launch_bounds__(1024) void k4_out(const float* __restrict__ x,
                                               const unsigned short* __restrict__ xbf,
                                               const unsigned short* __restrict__ D,
                                               const float* __restrict__ evec,
                                               float* __restrict__ out) {
  const int bid = blockIdx.x;                  // nwg = 1024
  const int wk  = (bid & 7) * 128 + (bid >> 3);
  const int b  = wk >> 5;
  const int mt = wk & 31;
  const int m0 = mt * 128;
  const float* __restrict__ xb = x + (size_t)b * SEQ * EMB;
  const unsigned short* __restrict__ xbb = xbf + (size_t)b * SEQ * EMB;
  const unsigned short* __restrict__ Db = D + (size_t)b * EMB * EMB;

  __shared__ unsigned short LA[128 * 40];     // 10240 B
  __shared__ unsigned short LB[512 * 40];     // 40960 B

  const int tid  = threadIdx.x;
  const int lane = tid & 63;
  const int wave = tid >> 6;        // 0..15
  const int wr = (wave >> 3) * 64;  // 0 or 64
  const int wc = (wave & 7) * 64;   // 0..448
  const int er  = lane & 15;
  const int kb8 = (lane >> 4) * 8;

  const int rsA = tid >> 3;         // 0..127
  const int kgA = tid & 7;          // 4 ushorts each
  const int rsB = tid >> 1;         // 0..511
  const int kgB = (tid & 1) * 16;   // 16 ushorts each (2x uint4)

  f32x4 acc[4][4];
#pragma unroll
  for (int i = 0; i < 4; ++i)
#pragma unroll
    for (int j = 0; j < 4; ++j) acc[i][j] = (f32x4){0.f, 0.f, 0.f, 0.f};

  uint2 ua;
  F4 fa;
  uint4 ub0, ub1;

  auto loadreg = [&](int k0) {
    if (XBF) {
      ua = *(const uint2*)&xbb[(size_t)(m0 + rsA) * EMB + k0 + kgA * 4];
    } else {
      fa.v = *(const float4*)&xb[(size_t)(m0 + rsA) * EMB + k0 + kgA * 4];
    }
    ub0 = *(const uint4*)&Db[(size_t)rsB * EMB + k0 + kgB];
    ub1 = *(const uint4*)&Db[(size_t)rsB * EMB + k0 + kgB + 8];
  };

  auto stage = [&]() {
    if (XBF) {
      *(uint2*)&LA[rsA * 40 + kgA * 4] = ua;
    } else {
      uint2 w; w.x = cvtpk(fa.f[0], fa.f[1]); w.y = cvtpk(fa.f[2], fa.f[3]);
      *(uint2*)&LA[rsA * 40 + kgA * 4] = w;
    }
    *(uint4*)&LB[rsB * 40 + kgB] = ub0;
    *(uint4*)&LB[rsB * 40 + kgB + 8] = ub1;
  };

  loadreg(0);

  for (int it = 0; it < 16; ++it) {
    __syncthreads();                 // previous compute's LDS reads done
    stage();
    __syncthreads();                 // tile ready
    if (it + 1 < 16) loadreg((it + 1) * 32);   // issue early

    bf16x8 bfr[4];
#pragma unroll
    for (int ns = 0; ns < 4; ++ns)
      bfr[ns] = *(const bf16x8*)&LB[(wc + ns * 16 + er) * 40 + kb8];
    {
      bf16x8 a0f = *(const bf16x8*)&LA[(wr + er) * 40 + kb8];
      bf16x8 a1f = *(const bf16x8*)&LA[(wr + 16 + er) * 40 + kb8];
#pragma unroll
      for (int ns = 0; ns < 4; ++ns) {
        acc[0][ns] = MFMA16(a0f, bfr[ns], acc[0][ns]);
        acc[1][ns] = MFMA16(a1f, bfr[ns], acc[1][ns]);
      }
    }
    {
      bf16x8 a2f = *(const bf16x8*)&LA[(wr + 32 + er) * 40 + kb8];
      bf16x8 a3f = *(const bf16x8*)&LA[(wr + 48 + er) * 40 + kb8];
#pragma unroll
      for (int ns = 0; ns < 4; ++ns) {
        acc[2][ns] = MFMA16(a2f, bfr[ns], acc[2][ns]);
        acc[3][ns] = MFMA16(a3f, bfr[ns], acc[3][ns]);
      }
    }
  }

  float ev4[4];
#pragma unroll
  for (int ns = 0; ns < 4; ++ns)
    ev4[ns] = evec[b * EMB + wc + ns * 16 + (lane & 15)];

#pragma unroll
  for (int ms = 0; ms < 4; ++ms)
#pragma unroll
    for (int ns = 0; ns < 4; ++ns)
#pragma unroll
      for (int r = 0; r < 4; ++r) {
        const int row = m0 + wr + ms * 16 + ((lane >> 4) * 4) + r;
        const int col = wc + ns * 16 + (lane & 15);
        __builtin_nontemporal_store(acc[ms][ns][r] + ev4[ns],
                                    &out[((size_t)b * SEQ + row) * EMB + col]);
      }
}

// ---------------------------------------------------------------------------
extern "C" void kernel_launch(void* const* d_in, const int* in_sizes, int n_in,
                              void* d_out, int out_size, void* d_ws, size_t ws_size,
                              hipStream_t stream) {
  (void)in_sizes; (void)n_in; (void)out_size;
  const float* x  = (const float*)d_in[0];
  const float* Wq = (const float*)d_in[1];
  const float* bq = (const float*)d_in[2];
  const float* Wk = (const float*)d_in[3];
  const float* bk = (const float*)d_in[4];
  const float* Wv = (const float*)d_in[5];
  const float* bv = (const float*)d_in[6];
  const float* Wo = (const float*)d_in[7];
  const float* bo = (const float*)d_in[8];
  float* out = (float*)d_out;

  char* ws = (char*)d_ws;
  const size_t MB = (size_t)1 << 20;
  const size_t XBF_BYTES = (size_t)BATCH * SEQ * EMB * 2;       // 128 MiB
  const size_t NEED2 = XBF_BYTES + 98 * MB + 256 * 1024;        // ~226 MiB
  const size_t NEED1 = XBF_BYTES + 66 * MB + 256 * 1024;        // ~194 MiB

  if (ws_size >= NEED2) {
    // xbf | P0,P1 (64M; Cm/Dm reuse after k2a) | A (32M) | svp(2) | ev
    unsigned short* xbf  = (unsigned short*)(ws);
    float*          P    = (float*)(ws + XBF_BYTES);
    unsigned short* Cm   = (unsigned short*)(ws + XBF_BYTES);
    unsigned short* Dm   = (unsigned short*)(ws + XBF_BYTES + 16 * MB);
    float*          A    = (float*)(ws + XBF_BYTES + 64 * MB);
    float*          svp  = (float*)(ws + XBF_BYTES + 98 * MB);
    float*          ev   = (float*)(ws + XBF_BYTES + 98 * MB + 192 * 1024);

    hipLaunchKernelGGL((k1_gram<2, true>), dim3(BATCH * 8),  dim3(1024), 0, stream, x, P, svp, xbf);
    hipLaunchKernelGGL((k2a_wqg<true>),    dim3(BATCH * 16), dim3(256), 0, stream, Wq, P, A);
    hipLaunchKernelGGL((k2b3a<2>),         dim3(BATCH * 8),  dim3(512), 0, stream, A, Wq, Wk, bq, bk, Wo, svp, Cm);
    hipLaunchKernelGGL(k3b_d,              dim3(BATCH * 16), dim3(256), 0, stream, Cm, Wv, bv, bo, Dm, ev);
    hipLaunchKernelGGL((k4_out<true>),     dim3(BATCH * 32), dim3(1024), 0, stream, x, xbf, Dm, ev, out);
  } else if (ws_size >= NEED1) {
    unsigned short* xbf  = (unsigned short*)(ws);
    float*          P    = (float*)(ws + XBF_BYTES);
    unsigned short* Cm   = (unsigned short*)(ws + XBF_BYTES);
    unsigned short* Dm   = (unsigned short*)(ws + XBF_BYTES + 16 * MB);
    float*          A    = (float*)(ws + XBF_BYTES + 32 * MB);
    float*          svp  = (float*)(ws + XBF_BYTES + 66 * MB);
    float*          ev   = (float*)(ws + XBF_BYTES + 66 * MB + 192 * 1024);

    hipLaunchKernelGGL((k1_gram<1, true>), dim3(BATCH * 4),  dim3(1024), 0, stream, x, P, svp, xbf);
    hipLaunchKernelGGL((k2a_wqg<false>),   dim3(BATCH * 16), dim3(256), 0, stream, Wq, P, A);
    hipLaunchKernelGGL((k2b3a<1>),         dim3(BATCH * 8),  dim3(512), 0, stream, A, Wq, Wk, bq, bk, Wo, svp, Cm);
    hipLaunchKernelGGL(k3b_d,              dim3(BATCH * 16), dim3(256), 0, stream, Cm, Wv, bv, bo, Dm, ev);
    hipLaunchKernelGGL((k4_out<true>),     dim3(BATCH * 32), dim3(1024), 0, stream, x, xbf, Dm, ev, out);
  } else {
    unsigned short* xbf  = (unsigned short*)(ws);   // unused
    float*          P    = (float*)(ws);
    unsigned short* Cm   = (unsigned short*)(ws);
    unsigned short* Dm   = (unsigned short*)(ws + 16 * MB);
    float*          A    = (float*)(ws + 32 * MB);
    float*          svp  = (float*)(ws + 66 * MB);
    float*          ev   = (float*)(ws + 66 * MB + 192 * 1024);

    hipLaunchKernelGGL((k1_gram<1, false>), dim3(BATCH * 4),  dim3(1024), 0, stream, x, P, svp, xbf);
    hipLaunchKernelGGL((k2a_wqg<false>),    dim3(BATCH * 16), dim3(256), 0, stream, Wq, P, A);
    hipLaunchKernelGGL((k2b3a<1>),          dim3(BATCH * 8),  dim3(512), 0, stream, A, Wq, Wk, bq, bk, Wo, svp, Cm);
    hipLaunchKernelGGL(k3b_d,               dim3(BATCH * 16), dim3(256), 0, stream, Cm, Wv, bv, bo, Dm, ev);
    hipLaunchKernelGGL((k4_out<false>),     dim3(BATCH * 32), dim3(1024), 0, stream, x, xbf, Dm, ev, out);
  }
}

// Round 15
// 354.565 us; speedup vs baseline: 1.0261x; 1.0261x over previous
//
#include <hip/hip_runtime.h>
#include <hip/hip_bf16.h>
#include <stdint.h>

#define BATCH 32
#define SEQ   4096
#define EMB   512
#define HEADS 8
#define HD    64
#define SCALE 0.125f   // 1/sqrt(64)

typedef __attribute__((ext_vector_type(8))) short bf16x8;
typedef __attribute__((ext_vector_type(4))) float f32x4;

__device__ __forceinline__ unsigned short f2bf(float f) {
    union { float f; unsigned int u; } v; v.f = f;
    unsigned int u = v.u;
    return (unsigned short)((u + 0x7FFFu + ((u >> 16) & 1u)) >> 16);
}
__device__ __forceinline__ float bf2f(unsigned short h) {
    union { unsigned int u; float f; } v; v.u = ((unsigned int)h) << 16;
    return v.f;
}
// HW packed fp32->bf16 (RNE): first arg -> bits[15:0], second -> bits[31:16]
__device__ __forceinline__ unsigned int cvtpk(float lo, float hi) {
    unsigned int r;
    asm("v_cvt_pk_bf16_f32 %0, %1, %2" : "=v"(r) : "v"(lo), "v"(hi));
    return r;
}
__device__ __forceinline__ float lo_as_f(unsigned int p) {
    union { unsigned int u; float f; } v; v.u = p << 16; return v.f;
}
__device__ __forceinline__ float hi_as_f(unsigned int p) {
    union { unsigned int u; float f; } v; v.u = p & 0xFFFF0000u; return v.f;
}

#define MFMA16(a, b, c) __builtin_amdgcn_mfma_f32_16x16x32_bf16((a), (b), (c), 0, 0, 0)

union F4 { float4 v; float f[4]; };
struct Regs { F4 a0, a1, a2, a3; };

// ---------------------------------------------------------------------------
// K1: P[c][b] = x_b[chunk c]^T x_b[chunk c] (fp32), svp[c][b] = chunk column
// sums (diag tiles), xbf = bf16(x) (diag tiles, XBF).
// TILE 256x256, 1024 thr / 16 waves. NCHUNK=2 -> grid 256 = 1/CU. (Round 8.)
// ---------------------------------------------------------------------------
template <int NCHUNK, bool XBF>
__global__ __launch_bounds__(1024) void k1_gram(const float* __restrict__ x,
                                                float* __restrict__ P,
                                                float* __restrict__ svp,
                                                unsigned short* __restrict__ xbf) {
  constexpr int KC  = SEQ / NCHUNK;
  constexpr int NIT = KC / 32;
  constexpr int NWG = BATCH * 4 * NCHUNK;
  constexpr int PER = NWG / 8;
  const int bid = blockIdx.x;
  const int wk  = (bid & 7) * PER + (bid >> 3);
  const int c   = (NCHUNK == 2) ? (wk & 1) : 0;
  const int tt  = (NCHUNK == 2) ? ((wk >> 1) & 3) : (wk & 3);
  const int b   = (NCHUNK == 2) ? (wk >> 3) : (wk >> 2);
  const int mt = (tt >> 1) & 1, nt = tt & 1;
  const int m0 = mt * 256, n0 = nt * 256;
  const bool diag = (mt == nt);
  const float* __restrict__ xb = x + (size_t)b * SEQ * EMB;
  const int kbeg = c * KC;

  __shared__ unsigned short L[2][64 * 148];   // [A/B], 37888 B
  __shared__ float SR[256][8];                // 8192 B

  const int tid  = threadIdx.x;
  const int lane = tid & 63;
  const int wave = tid >> 6;        // 0..15
  const int wr = (wave >> 2) * 64;
  const int wc = (wave & 3) * 64;
  const int er  = lane & 15;
  const int kb8 = (lane >> 4) * 8;

  const int fg   = lane;            // e-group: e = fg*4 + i  (256 cols)
  const int kgrp = wave >> 1;       // 0..7 -> k = kgrp*4 + j
  const bool isB = (wave & 1);
  const int pcol = isB ? n0 : m0;
  const bool active = (!diag) || (!isB);

  f32x4 acc[4][4];
#pragma unroll
  for (int i = 0; i < 4; ++i)
#pragma unroll
    for (int j = 0; j < 4; ++j) acc[i][j] = (f32x4){0.f, 0.f, 0.f, 0.f};

  float sacc[4] = {0.f, 0.f, 0.f, 0.f};

  Regs r0;

  auto loadreg = [&](int t) {
    const float* p = &xb[(size_t)(kbeg + t * 32 + kgrp * 4) * EMB + pcol + fg * 4];
    r0.a0.v = *(const float4*)p;
    r0.a1.v = *(const float4*)(p + EMB);
    r0.a2.v = *(const float4*)(p + 2 * EMB);
    r0.a3.v = *(const float4*)(p + 3 * EMB);
  };

  auto stage = [&](int t) {
    unsigned short* __restrict__ Ld = &L[isB ? 1 : 0][0];
#pragma unroll
    for (int i = 0; i < 4; ++i) {
      uint2 w;
      w.x = cvtpk(r0.a0.f[i], r0.a1.f[i]);
      w.y = cvtpk(r0.a2.f[i], r0.a3.f[i]);
      *(uint2*)&Ld[fg * 148 + i * 36 + kgrp * 4] = w;
    }
    if (diag) {
#pragma unroll
      for (int i = 0; i < 4; ++i)
        sacc[i] += (r0.a0.f[i] + r0.a1.f[i]) + (r0.a2.f[i] + r0.a3.f[i]);
      if (XBF) {
        unsigned short* xp = &xbf[((size_t)b * SEQ + kbeg + t * 32 + kgrp * 4) * EMB + m0 + fg * 4];
        uint2 xr;
        xr.x = cvtpk(r0.a0.f[0], r0.a0.f[1]); xr.y = cvtpk(r0.a0.f[2], r0.a0.f[3]);
        *(uint2*)&xp[0] = xr;
        xr.x = cvtpk(r0.a1.f[0], r0.a1.f[1]); xr.y = cvtpk(r0.a1.f[2], r0.a1.f[3]);
        *(uint2*)&xp[EMB] = xr;
        xr.x = cvtpk(r0.a2.f[0], r0.a2.f[1]); xr.y = cvtpk(r0.a2.f[2], r0.a2.f[3]);
        *(uint2*)&xp[2 * EMB] = xr;
        xr.x = cvtpk(r0.a3.f[0], r0.a3.f[1]); xr.y = cvtpk(r0.a3.f[2], r0.a3.f[3]);
        *(uint2*)&xp[3 * EMB] = xr;
      }
    }
  };

  auto frag = [&](const unsigned short* __restrict__ Ls, int e) -> bf16x8 {
    const int off = (e >> 2) * 148 + (e & 3) * 36 + kb8;
    union { bf16x8 v; uint2 u[2]; } r;
    r.u[0] = *(const uint2*)&Ls[off];
    r.u[1] = *(const uint2*)&Ls[off + 4];
    return r.v;
  };

  if (active) loadreg(0);

  for (int it = 0; it < NIT; ++it) {
    __syncthreads();                 // previous compute's LDS reads done
    if (active) stage(it);
    __syncthreads();                 // LDS tile ready
    if (active && (it + 1 < NIT)) loadreg(it + 1);   // issue early

    const unsigned short* __restrict__ LAs = &L[0][0];
    const unsigned short* __restrict__ LBs = diag ? LAs : &L[1][0];
    bf16x8 bfr[4];
#pragma unroll
    for (int ns = 0; ns < 4; ++ns) bfr[ns] = frag(LBs, wc + ns * 16 + er);
    {
      bf16x8 a0f = frag(LAs, wr + er);
      bf16x8 a1f = frag(LAs, wr + 16 + er);
#pragma unroll
      for (int ns = 0; ns < 4; ++ns) {
        acc[0][ns] = MFMA16(a0f, bfr[ns], acc[0][ns]);
        acc[1][ns] = MFMA16(a1f, bfr[ns], acc[1][ns]);
      }
    }
    {
      bf16x8 a2f = frag(LAs, wr + 32 + er);
      bf16x8 a3f = frag(LAs, wr + 48 + er);
#pragma unroll
      for (int ns = 0; ns < 4; ++ns) {
        acc[2][ns] = MFMA16(a2f, bfr[ns], acc[2][ns]);
        acc[3][ns] = MFMA16(a3f, bfr[ns], acc[3][ns]);
      }
    }
  }

  float* __restrict__ Pc = P + (size_t)(c * BATCH + b) * EMB * EMB;
#pragma unroll
  for (int ms = 0; ms < 4; ++ms)
#pragma unroll
    for (int ns = 0; ns < 4; ++ns)
#pragma unroll
      for (int r = 0; r < 4; ++r) {
        const int row = m0 + wr + ms * 16 + ((lane >> 4) * 4) + r;
        const int col = n0 + wc + ns * 16 + (lane & 15);
        Pc[(size_t)row * EMB + col] = acc[ms][ns][r];
      }

  if (diag) {
    __syncthreads();
    if (!isB) {
#pragma unroll
      for (int i = 0; i < 4; ++i) SR[fg * 4 + i][kgrp] = sacc[i];
    }
    __syncthreads();
    if (tid < 256) {
      float v = 0.f;
#pragma unroll
      for (int j = 0; j < 8; ++j) v += SR[tid][j];
      svp[(size_t)(c * BATCH + b) * EMB + m0 + tid] = v;
    }
  }
}

// ---------------------------------------------------------------------------
// K2a: A[b] = Wq @ G_b, G_b = P0_b (+ P1_b if TWO). 128^2 tile, 256 thr,
// register prefetch (round-13 proven).
// ---------------------------------------------------------------------------
template <bool TWO>
__global__ __launch_bounds__(256) void k2a_wqg(const float* __restrict__ Wq,
                                               const float* __restrict__ P,
                                               float* __restrict__ A) {
  const int bid = blockIdx.x;                 // nwg = 512
  const int wk  = (bid & 7) * 64 + (bid >> 3);
  const int b  = wk >> 4;
  const int mt = (wk >> 2) & 3;
  const int nt = wk & 3;
  const int m0 = mt * 128, n0 = nt * 128;
  const float* __restrict__ P0b = P + (size_t)b * EMB * EMB;
  const float* __restrict__ P1b = P + (size_t)(BATCH + b) * EMB * EMB;

  __shared__ unsigned short LA[128][40];
  __shared__ unsigned short LBhi[128][40];
  __shared__ unsigned short LBlo[128][40];

  const int tid  = threadIdx.x;
  const int lane = tid & 63;
  const int wave = tid >> 6;
  const int wr = (wave >> 1) * 64;
  const int wc = (wave & 1) * 64;

  f32x4 acc[4][4];
#pragma unroll
  for (int i = 0; i < 4; ++i)
#pragma unroll
    for (int j = 0; j < 4; ++j) acc[i][j] = (f32x4){0.f, 0.f, 0.f, 0.f};

  const int rA = tid >> 3, fgA = tid & 7;

  F4 ra[4], rb0[4], rb1[4];

  auto loadreg = [&](int k0) {
#pragma unroll
    for (int it = 0; it < 4; ++it) {
      const int r = rA + it * 32;
      ra[it].v  = *(const float4*)&Wq[(size_t)(m0 + r) * EMB + k0 + fgA * 4];
      rb0[it].v = *(const float4*)&P0b[(size_t)(n0 + r) * EMB + k0 + fgA * 4];
      if (TWO)
        rb1[it].v = *(const float4*)&P1b[(size_t)(n0 + r) * EMB + k0 + fgA * 4];
    }
  };

  auto stage = [&]() {
#pragma unroll
    for (int it = 0; it < 4; ++it) {
      const int r = rA + it * 32;
      uint2 u; u.x = cvtpk(ra[it].f[0], ra[it].f[1]); u.y = cvtpk(ra[it].f[2], ra[it].f[3]);
      *(uint2*)&LA[r][fgA * 4] = u;
      float v0 = rb0[it].f[0], v1 = rb0[it].f[1], v2 = rb0[it].f[2], v3 = rb0[it].f[3];
      if (TWO) { v0 += rb1[it].f[0]; v1 += rb1[it].f[1]; v2 += rb1[it].f[2]; v3 += rb1[it].f[3]; }
      uint2 h; h.x = cvtpk(v0, v1); h.y = cvtpk(v2, v3);
      uint2 l;
      l.x = cvtpk(v0 - lo_as_f(h.x), v1 - hi_as_f(h.x));
      l.y = cvtpk(v2 - lo_as_f(h.y), v3 - hi_as_f(h.y));
      *(uint2*)&LBhi[r][fgA * 4] = h;
      *(uint2*)&LBlo[r][fgA * 4] = l;
    }
  };

  loadreg(0);

  for (int k0 = 0; k0 < EMB; k0 += 32) {
    __syncthreads();
    stage();
    __syncthreads();
    if (k0 + 32 < EMB) loadreg(k0 + 32);   // issue early

    bf16x8 af[4], bh[4], bl[4];
#pragma unroll
    for (int ms = 0; ms < 4; ++ms)
      af[ms] = *(const bf16x8*)&LA[wr + ms*16 + (lane & 15)][(lane >> 4) * 8];
#pragma unroll
    for (int ns = 0; ns < 4; ++ns) {
      bh[ns] = *(const bf16x8*)&LBhi[wc + ns*16 + (lane & 15)][(lane >> 4) * 8];
      bl[ns] = *(const bf16x8*)&LBlo[wc + ns*16 + (lane & 15)][(lane >> 4) * 8];
    }
#pragma unroll
    for (int ms = 0; ms < 4; ++ms)
#pragma unroll
      for (int ns = 0; ns < 4; ++ns) {
        acc[ms][ns] = MFMA16(af[ms], bh[ns], acc[ms][ns]);
        acc[ms][ns] = MFMA16(af[ms], bl[ns], acc[ms][ns]);
      }
  }

  float* __restrict__ Ab = A + (size_t)b * EMB * EMB;
#pragma unroll
  for (int ms = 0; ms < 4; ++ms)
#pragma unroll
    for (int ns = 0; ns < 4; ++ns)
#pragma unroll
      for (int r = 0; r < 4; ++r) {
        const int row = m0 + wr + ms*16 + ((lane >> 4) * 4) + r;
        const int col = n0 + wc + ns*16 + (lane & 15);
        Ab[(size_t)row * EMB + col] = acc[ms][ns][r];
      }
}

// ---------------------------------------------------------------------------
// K2B3A (FUSED): per (b,h), 512 thr / 8 waves, grid 256.
// Waves 0-3: logits -> softmax -> attn^T in LDS. Waves 4-7: U/W + stage Wo
// rows 0..255 during the logits K-loop. Then all 8 waves: 2 passes of
// C = Wo_chunk @ attnT. attn never touches global.
// ---------------------------------------------------------------------------
template <int NCHUNK>
__global__ __launch_bounds__(512) void k2b3a(const float* __restrict__ A,
                                             const float* __restrict__ Wq,
                                             const float* __restrict__ Wk,
                                             const float* __restrict__ bq,
                                             const float* __restrict__ bk,
                                             const float* __restrict__ Wo,
                                             const float* __restrict__ svp,
                                             unsigned short* __restrict__ C) {
  const int blk = blockIdx.x;      // 256: b*8 + h
  const int b = blk >> 3;
  const int h = blk & 7;
  const float* __restrict__ Ab = A + (size_t)b * EMB * EMB + (size_t)h * HD * EMB;

  __shared__ unsigned short LAhi[64][40];   // 5120 B
  __shared__ unsigned short LAlo[64][40];   // 5120 B
  __shared__ unsigned short LB[64][40];     // 5120 B
  __shared__ float U[HD], W[HD];            // 512 B
  __shared__ unsigned short LBT[64][72];    // attn^T [kp][q], 9216 B
  __shared__ unsigned short LWO[256][72];   // Wo chunk, 36864 B   (total ~62 KB)

  const int tid  = threadIdx.x;
  const int lane = tid & 63;
  const int wave = tid >> 6;       // 0..7
  const bool qkw = (wave < 4);

  const int r8 = tid >> 3, fg8 = tid & 7;     // valid for tid < 256

  F4 va[2], vw[2];

  auto loadreg = [&](int k0) {
#pragma unroll
    for (int it = 0; it < 2; ++it) {
      const int r = r8 + it * 32;
      va[it].v = *(const float4*)&Ab[(size_t)r * EMB + k0 + fg8 * 4];
      vw[it].v = *(const float4*)&Wk[(size_t)(h*HD + r) * EMB + k0 + fg8 * 4];
    }
  };

  auto stage = [&]() {
#pragma unroll
    for (int it = 0; it < 2; ++it) {
      const int r = r8 + it * 32;
      uint2 h2; h2.x = cvtpk(va[it].f[0], va[it].f[1]); h2.y = cvtpk(va[it].f[2], va[it].f[3]);
      uint2 l2;
      l2.x = cvtpk(va[it].f[0] - lo_as_f(h2.x), va[it].f[1] - hi_as_f(h2.x));
      l2.y = cvtpk(va[it].f[2] - lo_as_f(h2.y), va[it].f[3] - hi_as_f(h2.y));
      *(uint2*)&LAhi[r][fg8*4] = h2;
      *(uint2*)&LAlo[r][fg8*4] = l2;
      uint2 ub; ub.x = cvtpk(vw[it].f[0], vw[it].f[1]); ub.y = cvtpk(vw[it].f[2], vw[it].f[3]);
      *(uint2*)&LB[r][fg8*4] = ub;
    }
  };

  if (qkw) loadreg(0);

  // waves 4-7: U = Wq_h @ s, W = Wk_h @ s (s = sum of chunk partials)
  if (!qkw) {
    const int t2 = tid - 256;
    if (t2 < 128) {
      const int q = t2 & 63;
      const float* __restrict__ wrow = (t2 < 64 ? Wq : Wk) + (size_t)(h * HD + q) * EMB;
      float a = 0.f;
      for (int i = 0; i < EMB; i += 4) {
        const float4 wv = *(const float4*)&wrow[i];
        float4 sv = *(const float4*)&svp[(size_t)b * EMB + i];
        if (NCHUNK == 2) {
          const float4 s1 = *(const float4*)&svp[(size_t)(BATCH + b) * EMB + i];
          sv.x += s1.x; sv.y += s1.y; sv.z += s1.z; sv.w += s1.w;
        }
        a += wv.x*sv.x + wv.y*sv.y + wv.z*sv.z + wv.w*sv.w;
      }
      if (t2 < 64) U[q] = a; else W[q] = a;
    }
  }

  f32x4 acc[4];
#pragma unroll
  for (int i = 0; i < 4; ++i) acc[i] = (f32x4){0.f, 0.f, 0.f, 0.f};

  for (int k0 = 0; k0 < EMB; k0 += 32) {
    __syncthreads();
    if (qkw) {
      stage();
    } else {
      // stage Wo rows (k0/32)*16 .. +15 of column block h (overlaps logits)
      const int t2 = tid - 256;
      const int row = (k0 >> 5) * 16 + (t2 >> 4);
      const int fg = t2 & 15;
      const float4 v = *(const float4*)&Wo[(size_t)row * EMB + h*HD + fg * 4];
      uint2 u; u.x = cvtpk(v.x, v.y); u.y = cvtpk(v.z, v.w);
      *(uint2*)&LWO[row][fg * 4] = u;
    }
    __syncthreads();
    if (qkw) {
      if (k0 + 32 < EMB) loadreg(k0 + 32);   // issue early

      const bf16x8 ah = *(const bf16x8*)&LAhi[wave*16 + (lane & 15)][(lane >> 4) * 8];
      const bf16x8 al = *(const bf16x8*)&LAlo[wave*16 + (lane & 15)][(lane >> 4) * 8];
#pragma unroll
      for (int ns = 0; ns < 4; ++ns) {
        const bf16x8 bb = *(const bf16x8*)&LB[ns*16 + (lane & 15)][(lane >> 4) * 8];
        acc[ns] = MFMA16(ah, bb, acc[ns]);
        acc[ns] = MFMA16(al, bb, acc[ns]);
      }
    }
  }

  // softmax epilogue (waves 0-3), write attn^T to LDS
  if (qkw) {
    const int colb = lane & 15;
    float bkv[4], wv_[4];
#pragma unroll
    for (int ns = 0; ns < 4; ++ns) {
      bkv[ns] = bk[h*HD + ns*16 + colb];
      wv_[ns] = W[ns*16 + colb];
    }
#pragma unroll
    for (int r = 0; r < 4; ++r) {
      const int row = wave*16 + ((lane >> 4) * 4) + r;
      const float bqv = bq[h*HD + row];
      const float uv  = U[row];
      float vals[4];
#pragma unroll
      for (int ns = 0; ns < 4; ++ns)
        vals[ns] = (acc[ns][r] + uv * bkv[ns] + bqv * wv_[ns] + 4096.f * bqv * bkv[ns]) * SCALE;
      float mx = fmaxf(fmaxf(vals[0], vals[1]), fmaxf(vals[2], vals[3]));
#pragma unroll
      for (int m = 1; m < 16; m <<= 1) mx = fmaxf(mx, __shfl_xor(mx, m));
      float sum = 0.f;
#pragma unroll
      for (int ns = 0; ns < 4; ++ns) { vals[ns] = expf(vals[ns] - mx); sum += vals[ns]; }
#pragma unroll
      for (int m = 1; m < 16; m <<= 1) sum += __shfl_xor(sum, m);
      const float inv = 1.f / sum;
#pragma unroll
      for (int ns = 0; ns < 4; ++ns)
        LBT[ns*16 + colb][row] = f2bf(vals[ns] * inv);
    }
  }
  __syncthreads();   // LBT + LWO(pass 0) ready

  // phase 2: C[p*256 + 0..255, h*64..h*64+63] = Wo_chunk @ attnT, 2 passes
  unsigned short* __restrict__ Cb = C + (size_t)b * EMB * EMB;
  for (int p = 0; p < 2; ++p) {
    if (p == 1) {
      __syncthreads();   // pass-0 LWO reads done
      // restage LWO with Wo rows 256..511 (all 512 threads)
      const int rr = tid >> 4;        // 0..31
      const int fg = tid & 15;
#pragma unroll
      for (int j = 0; j < 8; ++j) {
        const int row = rr + j * 32;
        const float4 v = *(const float4*)&Wo[(size_t)(256 + row) * EMB + h*HD + fg * 4];
        uint2 u; u.x = cvtpk(v.x, v.y); u.y = cvtpk(v.z, v.w);
        *(uint2*)&LWO[row][fg * 4] = u;
      }
      __syncthreads();
    }

    f32x4 acc2[2][4];
#pragma unroll
    for (int i = 0; i < 2; ++i)
#pragma unroll
      for (int j = 0; j < 4; ++j) acc2[i][j] = (f32x4){0.f, 0.f, 0.f, 0.f};

#pragma unroll
    for (int kk = 0; kk < 2; ++kk) {
      bf16x8 af[2], bfr[4];
#pragma unroll
      for (int ms = 0; ms < 2; ++ms)
        af[ms] = *(const bf16x8*)&LWO[wave*32 + ms*16 + (lane & 15)][kk*32 + (lane >> 4) * 8];
#pragma unroll
      for (int ns = 0; ns < 4; ++ns)
        bfr[ns] = *(const bf16x8*)&LBT[ns*16 + (lane & 15)][kk*32 + (lane >> 4) * 8];
#pragma unroll
      for (int ms = 0; ms < 2; ++ms)
#pragma unroll
        for (int ns = 0; ns < 4; ++ns)
          acc2[ms][ns] = MFMA16(af[ms], bfr[ns], acc2[ms][ns]);
    }

#pragma unroll
    for (int ms = 0; ms < 2; ++ms)
#pragma unroll
      for (int ns = 0; ns < 4; ++ns)
#pragma unroll
        for (int r = 0; r < 4; ++r) {
          const int row = p*256 + wave*32 + ms*16 + ((lane >> 4) * 4) + r;
          const int col = h*HD + ns*16 + (lane & 15);
          Cb[(size_t)row * EMB + col] = f2bf(acc2[ms][ns][r]);
        }
  }
}

// ---------------------------------------------------------------------------
// K3b: D[b] = C_b @ Wv (bf16 out) + FUSED e[b] = C_b @ bv + bo.
// Register prefetch (round-13). grid 32*16, block 256.
// ---------------------------------------------------------------------------
__global__ __launch_bounds__(256) void k3b_d(const unsigned short* __restrict__ C,
                                             const float* __restrict__ Wv,
                                             const float* __restrict__ bv,
                                             const float* __restrict__ bo,
                                             unsigned short* __restrict__ D,
                                             float* __restrict__ evec) {
  const int bid = blockIdx.x;                 // nwg = 512
  const int wk  = (bid & 7) * 64 + (bid >> 3);
  const int b  = wk >> 4;
  const int mt = (wk >> 2) & 3;
  const int nt = wk & 3;
  const int m0 = mt * 128, n0 = nt * 128;
  const unsigned short* __restrict__ Cb = C + (size_t)b * EMB * EMB;

  __shared__ unsigned short LA[128][40];
  __shared__ unsigned short LB[32 * 148];     // [n-subblocked][k] transposed Wv
  __shared__ float BV[EMB];

  const int tid  = threadIdx.x;
  const int lane = tid & 63;
  const int wave = tid >> 6;
  const int wr = (wave >> 1) * 64;
  const int wc = (wave & 1) * 64;
  const int er  = lane & 15;
  const int kb8 = (lane >> 4) * 8;

  const bool doE = (nt == 0);
  if (doE) {
    BV[tid] = bv[tid];
    BV[tid + 256] = bv[tid + 256];
  }

  f32x4 acc[4][4];
#pragma unroll
  for (int i = 0; i < 4; ++i)
#pragma unroll
    for (int j = 0; j < 4; ++j) acc[i][j] = (f32x4){0.f, 0.f, 0.f, 0.f};

  float eacc[4] = {0.f, 0.f, 0.f, 0.f};

  const int rA = tid >> 3, fgA = tid & 7;
  const int fgB = tid & 31;    // n-group: n = fgB*4 + i
  const int kgB = tid >> 5;    // k = kgB*4 + j

  ushort4 rc[4];
  F4 rb0, rb1, rb2, rb3;

  auto loadreg = [&](int k0) {
#pragma unroll
    for (int it = 0; it < 4; ++it) {
      const int r = rA + it * 32;
      rc[it] = *(const ushort4*)&Cb[(size_t)(m0 + r) * EMB + k0 + fgA * 4];
    }
    const float* p = &Wv[(size_t)(k0 + kgB * 4) * EMB + n0 + fgB * 4];
    rb0.v = *(const float4*)p;
    rb1.v = *(const float4*)(p + EMB);
    rb2.v = *(const float4*)(p + 2 * EMB);
    rb3.v = *(const float4*)(p + 3 * EMB);
  };

  auto stage = [&](int k0) {
    float bvr[4];
    if (doE) {
#pragma unroll
      for (int j = 0; j < 4; ++j) bvr[j] = BV[k0 + fgA * 4 + j];
    }
#pragma unroll
    for (int it = 0; it < 4; ++it) {
      const int r = rA + it * 32;
      *(ushort4*)&LA[r][fgA*4] = rc[it];
      if (doE)
        eacc[it] += bf2f(rc[it].x)*bvr[0] + bf2f(rc[it].y)*bvr[1]
                  + bf2f(rc[it].z)*bvr[2] + bf2f(rc[it].w)*bvr[3];
    }
#pragma unroll
    for (int i = 0; i < 4; ++i) {
      uint2 w;
      w.x = cvtpk(rb0.f[i], rb1.f[i]);
      w.y = cvtpk(rb2.f[i], rb3.f[i]);
      *(uint2*)&LB[fgB * 148 + i * 36 + kgB * 4] = w;
    }
  };

  loadreg(0);

  for (int k0 = 0; k0 < EMB; k0 += 32) {
    __syncthreads();
    stage(k0);
    __syncthreads();
    if (k0 + 32 < EMB) loadreg(k0 + 32);   // issue early

    bf16x8 af[4], bfr[4];
#pragma unroll
    for (int ms = 0; ms < 4; ++ms)
      af[ms] = *(const bf16x8*)&LA[wr + ms*16 + er][kb8];
#pragma unroll
    for (int ns = 0; ns < 4; ++ns) {
      const int e = wc + ns * 16 + er;
      const int off = (e >> 2) * 148 + (e & 3) * 36 + kb8;
      union { bf16x8 v; uint2 u[2]; } r;
      r.u[0] = *(const uint2*)&LB[off];
      r.u[1] = *(const uint2*)&LB[off + 4];
      bfr[ns] = r.v;
    }
#pragma unroll
    for (int ms = 0; ms < 4; ++ms)
#pragma unroll
      for (int ns = 0; ns < 4; ++ns)
        acc[ms][ns] = MFMA16(af[ms], bfr[ns], acc[ms][ns]);
  }

  unsigned short* __restrict__ Db = D + (size_t)b * EMB * EMB;
#pragma unroll
  for (int ms = 0; ms < 4; ++ms)
#pragma unroll
    for (int ns = 0; ns < 4; ++ns)
#pragma unroll
      for (int r = 0; r < 4; ++r) {
        const int row = m0 + wr + ms*16 + ((lane >> 4) * 4) + r;
        const int col = n0 + wc + ns*16 + (lane & 15);
        Db[(size_t)row * EMB + col] = f2bf(acc[ms][ns][r]);
      }

  if (doE) {
#pragma unroll
    for (int it = 0; it < 4; ++it) {
#pragma unroll
      for (int m = 1; m < 8; m <<= 1) eacc[it] += __shfl_xor(eacc[it], m);
      if (fgA == 0) {
        const int row = m0 + rA + it * 32;
        evec[b * EMB + row] = eacc[it] + bo[row];
      }
    }
  }
}

// ---------------------------------------------------------------------------
// K4: out[b] = x_b @ D_b^T + e_b. TILE 128x512, 1024 thr / 16 waves.
// grid 1024. PLAIN stores (round-14 lesson: nontemporal scalar stores
// added ~95 MB of partial-line write traffic and cost ~30 us).
// ---------------------------------------------------------------------------
template <bool XBF>
__global__ __launch_bounds__(1024) void k4_out(const float* __restrict__ x,
                                               const unsigned short* __restrict__ xbf,
                                               const unsigned short* __restrict__ D,
                                               const float* __restrict__ evec,
                                               float* __restrict__ out) {
  const int bid = blockIdx.x;                  // nwg = 1024
  const int wk  = (bid & 7) * 128 + (bid >> 3);
  const int b  = wk >> 5;
  const int mt = wk & 31;
  const int m0 = mt * 128;
  const float* __restrict__ xb = x + (size_t)b * SEQ * EMB;
  const unsigned short* __restrict__ xbb = xbf + (size_t)b * SEQ * EMB;
  const unsigned short* __restrict__ Db = D + (size_t)b * EMB * EMB;

  __shared__ unsigned short LA[128 * 40];     // 10240 B
  __shared__ unsigned short LB[512 * 40];     // 40960 B

  const int tid  = threadIdx.x;
  const int lane = tid & 63;
  const int wave = tid >> 6;        // 0..15
  const int wr = (wave >> 3) * 64;  // 0 or 64
  const int wc = (wave & 7) * 64;   // 0..448
  const int er  = lane & 15;
  const int kb8 = (lane >> 4) * 8;

  const int rsA = tid >> 3;         // 0..127
  const int kgA = tid & 7;          // 4 ushorts each
  const int rsB = tid >> 1;         // 0..511
  const int kgB = (tid & 1) * 16;   // 16 ushorts each (2x uint4)

  f32x4 acc[4][4];
#pragma unroll
  for (int i = 0; i < 4; ++i)
#pragma unroll
    for (int j = 0; j < 4; ++j) acc[i][j] = (f32x4){0.f, 0.f, 0.f, 0.f};

  uint2 ua;
  F4 fa;
  uint4 ub0, ub1;

  auto loadreg = [&](int k0) {
    if (XBF) {
      ua = *(const uint2*)&xbb[(size_t)(m0 + rsA) * EMB + k0 + kgA * 4];
    } else {
      fa.v = *(const float4*)&xb[(size_t)(m0 + rsA) * EMB + k0 + kgA * 4];
    }
    ub0 = *(const uint4*)&Db[(size_t)rsB * EMB + k0 + kgB];
    ub1 = *(const uint4*)&Db[(size_t)rsB * EMB + k0 + kgB + 8];
  };

  auto stage = [&]() {
    if (XBF) {
      *(uint2*)&LA[rsA * 40 + kgA * 4] = ua;
    } else {
      uint2 w; w.x = cvtpk(fa.f[0], fa.f[1]); w.y = cvtpk(fa.f[2], fa.f[3]);
      *(uint2*)&LA[rsA * 40 + kgA * 4] = w;
    }
    *(uint4*)&LB[rsB * 40 + kgB] = ub0;
    *(uint4*)&LB[rsB * 40 + kgB + 8] = ub1;
  };

  loadreg(0);

  for (int it = 0; it < 16; ++it) {
    __syncthreads();                 // previous compute's LDS reads done
    stage();
    __syncthreads();                 // tile ready
    if (it + 1 < 16) loadreg((it + 1) * 32);   // issue early

    bf16x8 bfr[4];
#pragma unroll
    for (int ns = 0; ns < 4; ++ns)
      bfr[ns] = *(const bf16x8*)&LB[(wc + ns * 16 + er) * 40 + kb8];
    {
      bf16x8 a0f = *(const bf16x8*)&LA[(wr + er) * 40 + kb8];
      bf16x8 a1f = *(const bf16x8*)&LA[(wr + 16 + er) * 40 + kb8];
#pragma unroll
      for (int ns = 0; ns < 4; ++ns) {
        acc[0][ns] = MFMA16(a0f, bfr[ns], acc[0][ns]);
        acc[1][ns] = MFMA16(a1f, bfr[ns], acc[1][ns]);
      }
    }
    {
      bf16x8 a2f = *(const bf16x8*)&LA[(wr + 32 + er) * 40 + kb8];
      bf16x8 a3f = *(const bf16x8*)&LA[(wr + 48 + er) * 40 + kb8];
#pragma unroll
      for (int ns = 0; ns < 4; ++ns) {
        acc[2][ns] = MFMA16(a2f, bfr[ns], acc[2][ns]);
        acc[3][ns] = MFMA16(a3f, bfr[ns], acc[3][ns]);
      }
    }
  }

  float ev4[4];
#pragma unroll
  for (int ns = 0; ns < 4; ++ns)
    ev4[ns] = evec[b * EMB + wc + ns * 16 + (lane & 15)];

#pragma unroll
  for (int ms = 0; ms < 4; ++ms)
#pragma unroll
    for (int ns = 0; ns < 4; ++ns)
#pragma unroll
      for (int r = 0; r < 4; ++r) {
        const int row = m0 + wr + ms * 16 + ((lane >> 4) * 4) + r;
        const int col = wc + ns * 16 + (lane & 15);
        out[((size_t)b * SEQ + row) * EMB + col] = acc[ms][ns][r] + ev4[ns];
      }
}

// ---------------------------------------------------------------------------
extern "C" void kernel_launch(void* const* d_in, const int* in_sizes, int n_in,
                              void* d_out, int out_size, void* d_ws, size_t ws_size,
                              hipStream_t stream) {
  (void)in_sizes; (void)n_in; (void)out_size;
  const float* x  = (const float*)d_in[0];
  const float* Wq = (const float*)d_in[1];
  const float* bq = (const float*)d_in[2];
  const float* Wk = (const float*)d_in[3];
  const float* bk = (const float*)d_in[4];
  const float* Wv = (const float*)d_in[5];
  const float* bv = (const float*)d_in[6];
  const float* Wo = (const float*)d_in[7];
  const float* bo = (const float*)d_in[8];
  float* out = (float*)d_out;

  char* ws = (char*)d_ws;
  const size_t MB = (size_t)1 << 20;
  const size_t XBF_BYTES = (size_t)BATCH * SEQ * EMB * 2;       // 128 MiB
  const size_t NEED2 = XBF_BYTES + 98 * MB + 256 * 1024;        // ~226 MiB
  const size_t NEED1 = XBF_BYTES + 66 * MB + 256 * 1024;        // ~194 MiB

  if (ws_size >= NEED2) {
    // xbf | P0,P1 (64M; Cm/Dm reuse after k2a) | A (32M) | svp(2) | ev
    unsigned short* xbf  = (unsigned short*)(ws);
    float*          P    = (float*)(ws + XBF_BYTES);
    unsigned short* Cm   = (unsigned short*)(ws + XBF_BYTES);
    unsigned short* Dm   = (unsigned short*)(ws + XBF_BYTES + 16 * MB);
    float*          A    = (float*)(ws + XBF_BYTES + 64 * MB);
    float*          svp  = (float*)(ws + XBF_BYTES + 98 * MB);
    float*          ev   = (float*)(ws + XBF_BYTES + 98 * MB + 192 * 1024);

    hipLaunchKernelGGL((k1_gram<2, true>), dim3(BATCH * 8),  dim3(1024), 0, stream, x, P, svp, xbf);
    hipLaunchKernelGGL((k2a_wqg<true>),    dim3(BATCH * 16), dim3(256), 0, stream, Wq, P, A);
    hipLaunchKernelGGL((k2b3a<2>),         dim3(BATCH * 8),  dim3(512), 0, stream, A, Wq, Wk, bq, bk, Wo, svp, Cm);
    hipLaunchKernelGGL(k3b_d,              dim3(BATCH * 16), dim3(256), 0, stream, Cm, Wv, bv, bo, Dm, ev);
    hipLaunchKernelGGL((k4_out<true>),     dim3(BATCH * 32), dim3(1024), 0, stream, x, xbf, Dm, ev, out);
  } else if (ws_size >= NEED1) {
    unsigned short* xbf  = (unsigned short*)(ws);
    float*          P    = (float*)(ws + XBF_BYTES);
    unsigned short* Cm   = (unsigned short*)(ws + XBF_BYTES);
    unsigned short* Dm   = (unsigned short*)(ws + XBF_BYTES + 16 * MB);
    float*          A    = (float*)(ws + XBF_BYTES + 32 * MB);
    float*          svp  = (float*)(ws + XBF_BYTES + 66 * MB);
    float*          ev   = (float*)(ws + XBF_BYTES + 66 * MB + 192 * 1024);

    hipLaunchKernelGGL((k1_gram<1, true>), dim3(BATCH * 4),  dim3(1024), 0, stream, x, P, svp, xbf);
    hipLaunchKernelGGL((k2a_wqg<false>),   dim3(BATCH * 16), dim3(256), 0, stream, Wq, P, A);
    hipLaunchKernelGGL((k2b3a<1>),         dim3(BATCH * 8),  dim3(512), 0, stream, A, Wq, Wk, bq, bk, Wo, svp, Cm);
    hipLaunchKernelGGL(k3b_d,              dim3(BATCH * 16), dim3(256), 0, stream, Cm, Wv, bv, bo, Dm, ev);
    hipLaunchKernelGGL((k4_out<true>),     dim3(BATCH * 32), dim3(1024), 0, stream, x, xbf, Dm, ev, out);
  } else {
    unsigned short* xbf  = (unsigned short*)(ws);   // unused
    float*          P    = (float*)(ws);
    unsigned short* Cm   = (unsigned short*)(ws);
    unsigned short* Dm   = (unsigned short*)(ws + 16 * MB);
    float*          A    = (float*)(ws + 32 * MB);
    float*          svp  = (float*)(ws + 66 * MB);
    float*          ev   = (float*)(ws + 66 * MB + 192 * 1024);

    hipLaunchKernelGGL((k1_gram<1, false>), dim3(BATCH * 4),  dim3(1024), 0, stream, x, P, svp, xbf);
    hipLaunchKernelGGL((k2a_wqg<false>),    dim3(BATCH * 16), dim3(256), 0, stream, Wq, P, A);
    hipLaunchKernelGGL((k2b3a<1>),          dim3(BATCH * 8),  dim3(512), 0, stream, A, Wq, Wk, bq, bk, Wo, svp, Cm);
    hipLaunchKernelGGL(k3b_d,               dim3(BATCH * 16), dim3(256), 0, stream, Cm, Wv, bv, bo, Dm, ev);
    hipLaunchKernelGGL((k4_out<false>),     dim3(BATCH * 32), dim3(1024), 0, stream, x, xbf, Dm, ev, out);
  }
}

// Round 16
// 347.457 us; speedup vs baseline: 1.0471x; 1.0205x over previous
//
#include <hip/hip_runtime.h>
#include <hip/hip_bf16.h>
#include <stdint.h>

#define BATCH 32
#define SEQ   4096
#define EMB   512
#define HEADS 8
#define HD    64
#define SCALE 0.125f   // 1/sqrt(64)

typedef __attribute__((ext_vector_type(8))) short bf16x8;
typedef __attribute__((ext_vector_type(4))) float f32x4;

__device__ __forceinline__ unsigned short f2bf(float f) {
    union { float f; unsigned int u; } v; v.f = f;
    unsigned int u = v.u;
    return (unsigned short)((u + 0x7FFFu + ((u >> 16) & 1u)) >> 16);
}
__device__ __forceinline__ float bf2f(unsigned short h) {
    union { unsigned int u; float f; } v; v.u = ((unsigned int)h) << 16;
    return v.f;
}
// HW packed fp32->bf16 (RNE): first arg -> bits[15:0], second -> bits[31:16]
__device__ __forceinline__ unsigned int cvtpk(float lo, float hi) {
    unsigned int r;
    asm("v_cvt_pk_bf16_f32 %0, %1, %2" : "=v"(r) : "v"(lo), "v"(hi));
    return r;
}
__device__ __forceinline__ float lo_as_f(unsigned int p) {
    union { unsigned int u; float f; } v; v.u = p << 16; return v.f;
}
__device__ __forceinline__ float hi_as_f(unsigned int p) {
    union { unsigned int u; float f; } v; v.u = p & 0xFFFF0000u; return v.f;
}

#define MFMA16(a, b, c) __builtin_amdgcn_mfma_f32_16x16x32_bf16((a), (b), (c), 0, 0, 0)

union F4 { float4 v; float f[4]; };
struct Regs { F4 a0, a1, a2, a3; };

// ---------------------------------------------------------------------------
// K1: P[c][b] = x_b[chunk c]^T x_b[chunk c] (fp32), svp[c][b] = chunk column
// sums (diag tiles), xbf = bf16(x) (diag tiles, XBF).
// TILE 256x256, 1024 thr / 16 waves. NCHUNK=2 -> grid 256 = 1/CU. (Round 8.)
// ---------------------------------------------------------------------------
template <int NCHUNK, bool XBF>
__global__ __launch_bounds__(1024) void k1_gram(const float* __restrict__ x,
                                                float* __restrict__ P,
                                                float* __restrict__ svp,
                                                unsigned short* __restrict__ xbf) {
  constexpr int KC  = SEQ / NCHUNK;
  constexpr int NIT = KC / 32;
  constexpr int NWG = BATCH * 4 * NCHUNK;
  constexpr int PER = NWG / 8;
  const int bid = blockIdx.x;
  const int wk  = (bid & 7) * PER + (bid >> 3);
  const int c   = (NCHUNK == 2) ? (wk & 1) : 0;
  const int tt  = (NCHUNK == 2) ? ((wk >> 1) & 3) : (wk & 3);
  const int b   = (NCHUNK == 2) ? (wk >> 3) : (wk >> 2);
  const int mt = (tt >> 1) & 1, nt = tt & 1;
  const int m0 = mt * 256, n0 = nt * 256;
  const bool diag = (mt == nt);
  const float* __restrict__ xb = x + (size_t)b * SEQ * EMB;
  const int kbeg = c * KC;

  __shared__ unsigned short L[2][64 * 148];   // [A/B], 37888 B
  __shared__ float SR[256][8];                // 8192 B

  const int tid  = threadIdx.x;
  const int lane = tid & 63;
  const int wave = tid >> 6;        // 0..15
  const int wr = (wave >> 2) * 64;
  const int wc = (wave & 3) * 64;
  const int er  = lane & 15;
  const int kb8 = (lane >> 4) * 8;

  const int fg   = lane;            // e-group: e = fg*4 + i  (256 cols)
  const int kgrp = wave >> 1;       // 0..7 -> k = kgrp*4 + j
  const bool isB = (wave & 1);
  const int pcol = isB ? n0 : m0;
  const bool active = (!diag) || (!isB);

  f32x4 acc[4][4];
#pragma unroll
  for (int i = 0; i < 4; ++i)
#pragma unroll
    for (int j = 0; j < 4; ++j) acc[i][j] = (f32x4){0.f, 0.f, 0.f, 0.f};

  float sacc[4] = {0.f, 0.f, 0.f, 0.f};

  Regs r0;

  auto loadreg = [&](int t) {
    const float* p = &xb[(size_t)(kbeg + t * 32 + kgrp * 4) * EMB + pcol + fg * 4];
    r0.a0.v = *(const float4*)p;
    r0.a1.v = *(const float4*)(p + EMB);
    r0.a2.v = *(const float4*)(p + 2 * EMB);
    r0.a3.v = *(const float4*)(p + 3 * EMB);
  };

  auto stage = [&](int t) {
    unsigned short* __restrict__ Ld = &L[isB ? 1 : 0][0];
#pragma unroll
    for (int i = 0; i < 4; ++i) {
      uint2 w;
      w.x = cvtpk(r0.a0.f[i], r0.a1.f[i]);
      w.y = cvtpk(r0.a2.f[i], r0.a3.f[i]);
      *(uint2*)&Ld[fg * 148 + i * 36 + kgrp * 4] = w;
    }
    if (diag) {
#pragma unroll
      for (int i = 0; i < 4; ++i)
        sacc[i] += (r0.a0.f[i] + r0.a1.f[i]) + (r0.a2.f[i] + r0.a3.f[i]);
      if (XBF) {
        unsigned short* xp = &xbf[((size_t)b * SEQ + kbeg + t * 32 + kgrp * 4) * EMB + m0 + fg * 4];
        uint2 xr;
        xr.x = cvtpk(r0.a0.f[0], r0.a0.f[1]); xr.y = cvtpk(r0.a0.f[2], r0.a0.f[3]);
        *(uint2*)&xp[0] = xr;
        xr.x = cvtpk(r0.a1.f[0], r0.a1.f[1]); xr.y = cvtpk(r0.a1.f[2], r0.a1.f[3]);
        *(uint2*)&xp[EMB] = xr;
        xr.x = cvtpk(r0.a2.f[0], r0.a2.f[1]); xr.y = cvtpk(r0.a2.f[2], r0.a2.f[3]);
        *(uint2*)&xp[2 * EMB] = xr;
        xr.x = cvtpk(r0.a3.f[0], r0.a3.f[1]); xr.y = cvtpk(r0.a3.f[2], r0.a3.f[3]);
        *(uint2*)&xp[3 * EMB] = xr;
      }
    }
  };

  auto frag = [&](const unsigned short* __restrict__ Ls, int e) -> bf16x8 {
    const int off = (e >> 2) * 148 + (e & 3) * 36 + kb8;
    union { bf16x8 v; uint2 u[2]; } r;
    r.u[0] = *(const uint2*)&Ls[off];
    r.u[1] = *(const uint2*)&Ls[off + 4];
    return r.v;
  };

  if (active) loadreg(0);

  for (int it = 0; it < NIT; ++it) {
    __syncthreads();                 // previous compute's LDS reads done
    if (active) stage(it);
    __syncthreads();                 // LDS tile ready
    if (active && (it + 1 < NIT)) loadreg(it + 1);   // issue early

    const unsigned short* __restrict__ LAs = &L[0][0];
    const unsigned short* __restrict__ LBs = diag ? LAs : &L[1][0];
    bf16x8 bfr[4];
#pragma unroll
    for (int ns = 0; ns < 4; ++ns) bfr[ns] = frag(LBs, wc + ns * 16 + er);
    {
      bf16x8 a0f = frag(LAs, wr + er);
      bf16x8 a1f = frag(LAs, wr + 16 + er);
#pragma unroll
      for (int ns = 0; ns < 4; ++ns) {
        acc[0][ns] = MFMA16(a0f, bfr[ns], acc[0][ns]);
        acc[1][ns] = MFMA16(a1f, bfr[ns], acc[1][ns]);
      }
    }
    {
      bf16x8 a2f = frag(LAs, wr + 32 + er);
      bf16x8 a3f = frag(LAs, wr + 48 + er);
#pragma unroll
      for (int ns = 0; ns < 4; ++ns) {
        acc[2][ns] = MFMA16(a2f, bfr[ns], acc[2][ns]);
        acc[3][ns] = MFMA16(a3f, bfr[ns], acc[3][ns]);
      }
    }
  }

  float* __restrict__ Pc = P + (size_t)(c * BATCH + b) * EMB * EMB;
#pragma unroll
  for (int ms = 0; ms < 4; ++ms)
#pragma unroll
    for (int ns = 0; ns < 4; ++ns)
#pragma unroll
      for (int r = 0; r < 4; ++r) {
        const int row = m0 + wr + ms * 16 + ((lane >> 4) * 4) + r;
        const int col = n0 + wc + ns * 16 + (lane & 15);
        Pc[(size_t)row * EMB + col] = acc[ms][ns][r];
      }

  if (diag) {
    __syncthreads();
    if (!isB) {
#pragma unroll
      for (int i = 0; i < 4; ++i) SR[fg * 4 + i][kgrp] = sacc[i];
    }
    __syncthreads();
    if (tid < 256) {
      float v = 0.f;
#pragma unroll
      for (int j = 0; j < 8; ++j) v += SR[tid][j];
      svp[(size_t)(c * BATCH + b) * EMB + m0 + tid] = v;
    }
  }
}

// ---------------------------------------------------------------------------
// K2a: A[b] = Wq @ G_b, G_b = P0_b (+ P1_b if TWO). 128^2 tile, 256 thr,
// register prefetch (round-13 proven).
// ---------------------------------------------------------------------------
template <bool TWO>
__global__ __launch_bounds__(256) void k2a_wqg(const float* __restrict__ Wq,
                                               const float* __restrict__ P,
                                               float* __restrict__ A) {
  const int bid = blockIdx.x;                 // nwg = 512
  const int wk  = (bid & 7) * 64 + (bid >> 3);
  const int b  = wk >> 4;
  const int mt = (wk >> 2) & 3;
  const int nt = wk & 3;
  const int m0 = mt * 128, n0 = nt * 128;
  const float* __restrict__ P0b = P + (size_t)b * EMB * EMB;
  const float* __restrict__ P1b = P + (size_t)(BATCH + b) * EMB * EMB;

  __shared__ unsigned short LA[128][40];
  __shared__ unsigned short LBhi[128][40];
  __shared__ unsigned short LBlo[128][40];

  const int tid  = threadIdx.x;
  const int lane = tid & 63;
  const int wave = tid >> 6;
  const int wr = (wave >> 1) * 64;
  const int wc = (wave & 1) * 64;

  f32x4 acc[4][4];
#pragma unroll
  for (int i = 0; i < 4; ++i)
#pragma unroll
    for (int j = 0; j < 4; ++j) acc[i][j] = (f32x4){0.f, 0.f, 0.f, 0.f};

  const int rA = tid >> 3, fgA = tid & 7;

  F4 ra[4], rb0[4], rb1[4];

  auto loadreg = [&](int k0) {
#pragma unroll
    for (int it = 0; it < 4; ++it) {
      const int r = rA + it * 32;
      ra[it].v  = *(const float4*)&Wq[(size_t)(m0 + r) * EMB + k0 + fgA * 4];
      rb0[it].v = *(const float4*)&P0b[(size_t)(n0 + r) * EMB + k0 + fgA * 4];
      if (TWO)
        rb1[it].v = *(const float4*)&P1b[(size_t)(n0 + r) * EMB + k0 + fgA * 4];
    }
  };

  auto stage = [&]() {
#pragma unroll
    for (int it = 0; it < 4; ++it) {
      const int r = rA + it * 32;
      uint2 u; u.x = cvtpk(ra[it].f[0], ra[it].f[1]); u.y = cvtpk(ra[it].f[2], ra[it].f[3]);
      *(uint2*)&LA[r][fgA * 4] = u;
      float v0 = rb0[it].f[0], v1 = rb0[it].f[1], v2 = rb0[it].f[2], v3 = rb0[it].f[3];
      if (TWO) { v0 += rb1[it].f[0]; v1 += rb1[it].f[1]; v2 += rb1[it].f[2]; v3 += rb1[it].f[3]; }
      uint2 h; h.x = cvtpk(v0, v1); h.y = cvtpk(v2, v3);
      uint2 l;
      l.x = cvtpk(v0 - lo_as_f(h.x), v1 - hi_as_f(h.x));
      l.y = cvtpk(v2 - lo_as_f(h.y), v3 - hi_as_f(h.y));
      *(uint2*)&LBhi[r][fgA * 4] = h;
      *(uint2*)&LBlo[r][fgA * 4] = l;
    }
  };

  loadreg(0);

  for (int k0 = 0; k0 < EMB; k0 += 32) {
    __syncthreads();
    stage();
    __syncthreads();
    if (k0 + 32 < EMB) loadreg(k0 + 32);   // issue early

    bf16x8 af[4], bh[4], bl[4];
#pragma unroll
    for (int ms = 0; ms < 4; ++ms)
      af[ms] = *(const bf16x8*)&LA[wr + ms*16 + (lane & 15)][(lane >> 4) * 8];
#pragma unroll
    for (int ns = 0; ns < 4; ++ns) {
      bh[ns] = *(const bf16x8*)&LBhi[wc + ns*16 + (lane & 15)][(lane >> 4) * 8];
      bl[ns] = *(const bf16x8*)&LBlo[wc + ns*16 + (lane & 15)][(lane >> 4) * 8];
    }
#pragma unroll
    for (int ms = 0; ms < 4; ++ms)
#pragma unroll
      for (int ns = 0; ns < 4; ++ns) {
        acc[ms][ns] = MFMA16(af[ms], bh[ns], acc[ms][ns]);
        acc[ms][ns] = MFMA16(af[ms], bl[ns], acc[ms][ns]);
      }
  }

  float* __restrict__ Ab = A + (size_t)b * EMB * EMB;
#pragma unroll
  for (int ms = 0; ms < 4; ++ms)
#pragma unroll
    for (int ns = 0; ns < 4; ++ns)
#pragma unroll
      for (int r = 0; r < 4; ++r) {
        const int row = m0 + wr + ms*16 + ((lane >> 4) * 4) + r;
        const int col = n0 + wc + ns*16 + (lane & 15);
        Ab[(size_t)row * EMB + col] = acc[ms][ns][r];
      }
}

// ---------------------------------------------------------------------------
// K2b: per (b,h): logits = A_h @ Wk_h^T + bias terms, *1/8, softmax rows,
// store attn bf16 (64x64). Register prefetch (round-13 proven).
// ---------------------------------------------------------------------------
template <int NCHUNK>
__global__ __launch_bounds__(256) void k2b_logits(const float* __restrict__ A,
                                                  const float* __restrict__ Wq,
                                                  const float* __restrict__ Wk,
                                                  const float* __restrict__ bq,
                                                  const float* __restrict__ bk,
                                                  const float* __restrict__ svp,
                                                  unsigned short* __restrict__ attn) {
  const int blk = blockIdx.x;
  const int b = blk >> 3;
  const int h = blk & 7;
  const float* __restrict__ Ab = A + (size_t)b * EMB * EMB + (size_t)h * HD * EMB;

  __shared__ unsigned short LAhi[64][40];
  __shared__ unsigned short LAlo[64][40];
  __shared__ unsigned short LB[64][40];
  __shared__ float U[HD], W[HD];

  const int tid  = threadIdx.x;
  const int lane = tid & 63;
  const int wave = tid >> 6;

  const int r8 = tid >> 3, fg8 = tid & 7;

  F4 va[2], vw[2];

  auto loadreg = [&](int k0) {
#pragma unroll
    for (int it = 0; it < 2; ++it) {
      const int r = r8 + it * 32;
      va[it].v = *(const float4*)&Ab[(size_t)r * EMB + k0 + fg8 * 4];
      vw[it].v = *(const float4*)&Wk[(size_t)(h*HD + r) * EMB + k0 + fg8 * 4];
    }
  };

  auto stage = [&]() {
#pragma unroll
    for (int it = 0; it < 2; ++it) {
      const int r = r8 + it * 32;
      uint2 h2; h2.x = cvtpk(va[it].f[0], va[it].f[1]); h2.y = cvtpk(va[it].f[2], va[it].f[3]);
      uint2 l2;
      l2.x = cvtpk(va[it].f[0] - lo_as_f(h2.x), va[it].f[1] - hi_as_f(h2.x));
      l2.y = cvtpk(va[it].f[2] - lo_as_f(h2.y), va[it].f[3] - hi_as_f(h2.y));
      *(uint2*)&LAhi[r][fg8*4] = h2;
      *(uint2*)&LAlo[r][fg8*4] = l2;
      uint2 ub; ub.x = cvtpk(vw[it].f[0], vw[it].f[1]); ub.y = cvtpk(vw[it].f[2], vw[it].f[3]);
      *(uint2*)&LB[r][fg8*4] = ub;
    }
  };

  loadreg(0);

  // u = Wq_h @ s, w = Wk_h @ s   (s = sum of chunk partials)
  if (tid < 128) {
    const int q = tid & 63;
    const float* __restrict__ wrow = (tid < 64 ? Wq : Wk) + (size_t)(h * HD + q) * EMB;
    float a = 0.f;
    for (int i = 0; i < EMB; i += 4) {
      const float4 wv = *(const float4*)&wrow[i];
      float4 sv = *(const float4*)&svp[(size_t)b * EMB + i];
      if (NCHUNK == 2) {
        const float4 s1 = *(const float4*)&svp[(size_t)(BATCH + b) * EMB + i];
        sv.x += s1.x; sv.y += s1.y; sv.z += s1.z; sv.w += s1.w;
      }
      a += wv.x*sv.x + wv.y*sv.y + wv.z*sv.z + wv.w*sv.w;
    }
    if (tid < 64) U[q] = a; else W[q] = a;
  }

  f32x4 acc[4];
#pragma unroll
  for (int i = 0; i < 4; ++i) acc[i] = (f32x4){0.f, 0.f, 0.f, 0.f};

  for (int k0 = 0; k0 < EMB; k0 += 32) {
    __syncthreads();
    stage();
    __syncthreads();
    if (k0 + 32 < EMB) loadreg(k0 + 32);   // issue early

    const bf16x8 ah = *(const bf16x8*)&LAhi[wave*16 + (lane & 15)][(lane >> 4) * 8];
    const bf16x8 al = *(const bf16x8*)&LAlo[wave*16 + (lane & 15)][(lane >> 4) * 8];
#pragma unroll
    for (int ns = 0; ns < 4; ++ns) {
      const bf16x8 bb = *(const bf16x8*)&LB[ns*16 + (lane & 15)][(lane >> 4) * 8];
      acc[ns] = MFMA16(ah, bb, acc[ns]);
      acc[ns] = MFMA16(al, bb, acc[ns]);
    }
  }

  // epilogue: bias + scale + softmax over cols (axis k')
  const int colb = lane & 15;
  float bkv[4], wv_[4];
#pragma unroll
  for (int ns = 0; ns < 4; ++ns) {
    bkv[ns] = bk[h*HD + ns*16 + colb];
    wv_[ns] = W[ns*16 + colb];
  }
  unsigned short* __restrict__ ab = attn + (size_t)(b * HEADS + h) * HD * HD;
#pragma unroll
  for (int r = 0; r < 4; ++r) {
    const int row = wave*16 + ((lane >> 4) * 4) + r;
    const float bqv = bq[h*HD + row];
    const float uv  = U[row];
    float vals[4];
#pragma unroll
    for (int ns = 0; ns < 4; ++ns)
      vals[ns] = (acc[ns][r] + uv * bkv[ns] + bqv * wv_[ns] + 4096.f * bqv * bkv[ns]) * SCALE;
    float mx = fmaxf(fmaxf(vals[0], vals[1]), fmaxf(vals[2], vals[3]));
#pragma unroll
    for (int m = 1; m < 16; m <<= 1) mx = fmaxf(mx, __shfl_xor(mx, m));
    float sum = 0.f;
#pragma unroll
    for (int ns = 0; ns < 4; ++ns) { vals[ns] = expf(vals[ns] - mx); sum += vals[ns]; }
#pragma unroll
    for (int m = 1; m < 16; m <<= 1) sum += __shfl_xor(sum, m);
    const float inv = 1.f / sum;
#pragma unroll
    for (int ns = 0; ns < 4; ++ns)
      ab[(size_t)row * HD + ns*16 + colb] = f2bf(vals[ns] * inv);
  }
}

// ---------------------------------------------------------------------------
// K3a: C[b][:, h*64..] = Wo[:, h*64..] @ attn_h   (bf16 out). K=64.
// ---------------------------------------------------------------------------
__global__ __launch_bounds__(256) void k3a_c(const float* __restrict__ Wo,
                                             const unsigned short* __restrict__ attn,
                                             unsigned short* __restrict__ C) {
  const int blk = blockIdx.x;
  const int b  = blk >> 5;
  const int h  = (blk >> 2) & 7;
  const int mt = blk & 3;
  const int m0 = mt * 128;

  __shared__ unsigned short LA[128][72];
  __shared__ unsigned short LB[64][72];

  const int tid  = threadIdx.x;
  const int lane = tid & 63;
  const int wave = tid >> 6;

  {
    const int r  = tid >> 4;   // 0..15
    const int fg = tid & 15;
#pragma unroll
    for (int it = 0; it < 8; ++it) {
      const int rr = r + it * 16;
      const float4 v = *(const float4*)&Wo[(size_t)(m0 + rr) * EMB + h*HD + fg * 4];
      uint2 u; u.x = cvtpk(v.x, v.y); u.y = cvtpk(v.z, v.w);
      *(uint2*)&LA[rr][fg * 4] = u;
    }
  }
  {
    const unsigned short* __restrict__ ab = attn + (size_t)(b * HEADS + h) * HD * HD;
#pragma unroll
    for (int it = 0; it < 16; ++it) {
      const int f  = tid + 256 * it;
      const int q  = f >> 6;
      const int kp = f & 63;
      LB[kp][q] = ab[q * HD + kp];   // transpose
    }
  }
  __syncthreads();

  f32x4 acc[2][4];
#pragma unroll
  for (int i = 0; i < 2; ++i)
#pragma unroll
    for (int j = 0; j < 4; ++j) acc[i][j] = (f32x4){0.f, 0.f, 0.f, 0.f};

#pragma unroll
  for (int kk = 0; kk < 2; ++kk) {
    bf16x8 af[2], bfr[4];
#pragma unroll
    for (int ms = 0; ms < 2; ++ms)
      af[ms] = *(const bf16x8*)&LA[wave*32 + ms*16 + (lane & 15)][kk*32 + (lane >> 4) * 8];
#pragma unroll
    for (int ns = 0; ns < 4; ++ns)
      bfr[ns] = *(const bf16x8*)&LB[ns*16 + (lane & 15)][kk*32 + (lane >> 4) * 8];
#pragma unroll
    for (int ms = 0; ms < 2; ++ms)
#pragma unroll
      for (int ns = 0; ns < 4; ++ns)
        acc[ms][ns] = MFMA16(af[ms], bfr[ns], acc[ms][ns]);
  }

  unsigned short* __restrict__ Cb = C + (size_t)b * EMB * EMB;
#pragma unroll
  for (int ms = 0; ms < 2; ++ms)
#pragma unroll
    for (int ns = 0; ns < 4; ++ns)
#pragma unroll
      for (int r = 0; r < 4; ++r) {
        const int row = m0 + wave*32 + ms*16 + ((lane >> 4) * 4) + r;
        const int col = h*HD + ns*16 + (lane & 15);
        Cb[(size_t)row * EMB + col] = f2bf(acc[ms][ns][r]);
      }
}

// ---------------------------------------------------------------------------
// K3b: D[b] = C_b @ Wv (bf16 out) + FUSED e[b] = C_b @ bv + bo.
// Register prefetch (round-13). grid 32*16, block 256.
// ---------------------------------------------------------------------------
__global__ __launch_bounds__(256) void k3b_d(const unsigned short* __restrict__ C,
                                             const float* __restrict__ Wv,
                                             const float* __restrict__ bv,
                                             const float* __restrict__ bo,
                                             unsigned short* __restrict__ D,
                                             float* __restrict__ evec) {
  const int bid = blockIdx.x;                 // nwg = 512
  const int wk  = (bid & 7) * 64 + (bid >> 3);
  const int b  = wk >> 4;
  const int mt = (wk >> 2) & 3;
  const int nt = wk & 3;
  const int m0 = mt * 128, n0 = nt * 128;
  const unsigned short* __restrict__ Cb = C + (size_t)b * EMB * EMB;

  __shared__ unsigned short LA[128][40];
  __shared__ unsigned short LB[32 * 148];     // [n-subblocked][k] transposed Wv
  __shared__ float BV[EMB];

  const int tid  = threadIdx.x;
  const int lane = tid & 63;
  const int wave = tid >> 6;
  const int wr = (wave >> 1) * 64;
  const int wc = (wave & 1) * 64;
  const int er  = lane & 15;
  const int kb8 = (lane >> 4) * 8;

  const bool doE = (nt == 0);
  if (doE) {
    BV[tid] = bv[tid];
    BV[tid + 256] = bv[tid + 256];
  }

  f32x4 acc[4][4];
#pragma unroll
  for (int i = 0; i < 4; ++i)
#pragma unroll
    for (int j = 0; j < 4; ++j) acc[i][j] = (f32x4){0.f, 0.f, 0.f, 0.f};

  float eacc[4] = {0.f, 0.f, 0.f, 0.f};

  const int rA = tid >> 3, fgA = tid & 7;
  const int fgB = tid & 31;    // n-group: n = fgB*4 + i
  const int kgB = tid >> 5;    // k = kgB*4 + j

  ushort4 rc[4];
  F4 rb0, rb1, rb2, rb3;

  auto loadreg = [&](int k0) {
#pragma unroll
    for (int it = 0; it < 4; ++it) {
      const int r = rA + it * 32;
      rc[it] = *(const ushort4*)&Cb[(size_t)(m0 + r) * EMB + k0 + fgA * 4];
    }
    const float* p = &Wv[(size_t)(k0 + kgB * 4) * EMB + n0 + fgB * 4];
    rb0.v = *(const float4*)p;
    rb1.v = *(const float4*)(p + EMB);
    rb2.v = *(const float4*)(p + 2 * EMB);
    rb3.v = *(const float4*)(p + 3 * EMB);
  };

  auto stage = [&](int k0) {
    float bvr[4];
    if (doE) {
#pragma unroll
      for (int j = 0; j < 4; ++j) bvr[j] = BV[k0 + fgA * 4 + j];
    }
#pragma unroll
    for (int it = 0; it < 4; ++it) {
      const int r = rA + it * 32;
      *(ushort4*)&LA[r][fgA*4] = rc[it];
      if (doE)
        eacc[it] += bf2f(rc[it].x)*bvr[0] + bf2f(rc[it].y)*bvr[1]
                  + bf2f(rc[it].z)*bvr[2] + bf2f(rc[it].w)*bvr[3];
    }
#pragma unroll
    for (int i = 0; i < 4; ++i) {
      uint2 w;
      w.x = cvtpk(rb0.f[i], rb1.f[i]);
      w.y = cvtpk(rb2.f[i], rb3.f[i]);
      *(uint2*)&LB[fgB * 148 + i * 36 + kgB * 4] = w;
    }
  };

  loadreg(0);

  for (int k0 = 0; k0 < EMB; k0 += 32) {
    __syncthreads();
    stage(k0);
    __syncthreads();
    if (k0 + 32 < EMB) loadreg(k0 + 32);   // issue early

    bf16x8 af[4], bfr[4];
#pragma unroll
    for (int ms = 0; ms < 4; ++ms)
      af[ms] = *(const bf16x8*)&LA[wr + ms*16 + er][kb8];
#pragma unroll
    for (int ns = 0; ns < 4; ++ns) {
      const int e = wc + ns * 16 + er;
      const int off = (e >> 2) * 148 + (e & 3) * 36 + kb8;
      union { bf16x8 v; uint2 u[2]; } r;
      r.u[0] = *(const uint2*)&LB[off];
      r.u[1] = *(const uint2*)&LB[off + 4];
      bfr[ns] = r.v;
    }
#pragma unroll
    for (int ms = 0; ms < 4; ++ms)
#pragma unroll
      for (int ns = 0; ns < 4; ++ns)
        acc[ms][ns] = MFMA16(af[ms], bfr[ns], acc[ms][ns]);
  }

  unsigned short* __restrict__ Db = D + (size_t)b * EMB * EMB;
#pragma unroll
  for (int ms = 0; ms < 4; ++ms)
#pragma unroll
    for (int ns = 0; ns < 4; ++ns)
#pragma unroll
      for (int r = 0; r < 4; ++r) {
        const int row = m0 + wr + ms*16 + ((lane >> 4) * 4) + r;
        const int col = n0 + wc + ns*16 + (lane & 15);
        Db[(size_t)row * EMB + col] = f2bf(acc[ms][ns][r]);
      }

  if (doE) {
#pragma unroll
    for (int it = 0; it < 4; ++it) {
#pragma unroll
      for (int m = 1; m < 8; m <<= 1) eacc[it] += __shfl_xor(eacc[it], m);
      if (fgA == 0) {
        const int row = m0 + rA + it * 32;
        evec[b * EMB + row] = eacc[it] + bo[row];
      }
    }
  }
}

// ---------------------------------------------------------------------------
// K4: out[b] = x_b @ D_b^T + e_b. TILE 128x512, 1024 thr / 16 waves.
// grid 1024. PLAIN stores. (Round-13 proven.)
// ---------------------------------------------------------------------------
template <bool XBF>
__global__ __launch_bounds__(1024) void k4_out(const float* __restrict__ x,
                                               const unsigned short* __restrict__ xbf,
                                               const unsigned short* __restrict__ D,
                                               const float* __restrict__ evec,
                                               float* __restrict__ out) {
  const int bid = blockIdx.x;                  // nwg = 1024
  const int wk  = (bid & 7) * 128 + (bid >> 3);
  const int b  = wk >> 5;
  const int mt = wk & 31;
  const int m0 = mt * 128;
  const float* __restrict__ xb = x + (size_t)b * SEQ * EMB;
  const unsigned short* __restrict__ xbb = xbf + (size_t)b * SEQ * EMB;
  const unsigned short* __restrict__ Db = D + (size_t)b * EMB * EMB;

  __shared__ unsigned short LA[128 * 40];     // 10240 B
  __shared__ unsigned short LB[512 * 40];     // 40960 B

  const int tid  = threadIdx.x;
  const int lane = tid & 63;
  const int wave = tid >> 6;        // 0..15
  const int wr = (wave >> 3) * 64;  // 0 or 64
  const int wc = (wave & 7) * 64;   // 0..448
  const int er  = lane & 15;
  const int kb8 = (lane >> 4) * 8;

  const int rsA = tid >> 3;         // 0..127
  const int kgA = tid & 7;          // 4 ushorts each
  const int rsB = tid >> 1;         // 0..511
  const int kgB = (tid & 1) * 16;   // 16 ushorts each (2x uint4)

  f32x4 acc[4][4];
#pragma unroll
  for (int i = 0; i < 4; ++i)
#pragma unroll
    for (int j = 0; j < 4; ++j) acc[i][j] = (f32x4){0.f, 0.f, 0.f, 0.f};

  uint2 ua;
  F4 fa;
  uint4 ub0, ub1;

  auto loadreg = [&](int k0) {
    if (XBF) {
      ua = *(const uint2*)&xbb[(size_t)(m0 + rsA) * EMB + k0 + kgA * 4];
    } else {
      fa.v = *(const float4*)&xb[(size_t)(m0 + rsA) * EMB + k0 + kgA * 4];
    }
    ub0 = *(const uint4*)&Db[(size_t)rsB * EMB + k0 + kgB];
    ub1 = *(const uint4*)&Db[(size_t)rsB * EMB + k0 + kgB + 8];
  };

  auto stage = [&]() {
    if (XBF) {
      *(uint2*)&LA[rsA * 40 + kgA * 4] = ua;
    } else {
      uint2 w; w.x = cvtpk(fa.f[0], fa.f[1]); w.y = cvtpk(fa.f[2], fa.f[3]);
      *(uint2*)&LA[rsA * 40 + kgA * 4] = w;
    }
    *(uint4*)&LB[rsB * 40 + kgB] = ub0;
    *(uint4*)&LB[rsB * 40 + kgB + 8] = ub1;
  };

  loadreg(0);

  for (int it = 0; it < 16; ++it) {
    __syncthreads();                 // previous compute's LDS reads done
    stage();
    __syncthreads();                 // tile ready
    if (it + 1 < 16) loadreg((it + 1) * 32);   // issue early

    bf16x8 bfr[4];
#pragma unroll
    for (int ns = 0; ns < 4; ++ns)
      bfr[ns] = *(const bf16x8*)&LB[(wc + ns * 16 + er) * 40 + kb8];
    {
      bf16x8 a0f = *(const bf16x8*)&LA[(wr + er) * 40 + kb8];
      bf16x8 a1f = *(const bf16x8*)&LA[(wr + 16 + er) * 40 + kb8];
#pragma unroll
      for (int ns = 0; ns < 4; ++ns) {
        acc[0][ns] = MFMA16(a0f, bfr[ns], acc[0][ns]);
        acc[1][ns] = MFMA16(a1f, bfr[ns], acc[1][ns]);
      }
    }
    {
      bf16x8 a2f = *(const bf16x8*)&LA[(wr + 32 + er) * 40 + kb8];
      bf16x8 a3f = *(const bf16x8*)&LA[(wr + 48 + er) * 40 + kb8];
#pragma unroll
      for (int ns = 0; ns < 4; ++ns) {
        acc[2][ns] = MFMA16(a2f, bfr[ns], acc[2][ns]);
        acc[3][ns] = MFMA16(a3f, bfr[ns], acc[3][ns]);
      }
    }
  }

  float ev4[4];
#pragma unroll
  for (int ns = 0; ns < 4; ++ns)
    ev4[ns] = evec[b * EMB + wc + ns * 16 + (lane & 15)];

#pragma unroll
  for (int ms = 0; ms < 4; ++ms)
#pragma unroll
    for (int ns = 0; ns < 4; ++ns)
#pragma unroll
      for (int r = 0; r < 4; ++r) {
        const int row = m0 + wr + ms * 16 + ((lane >> 4) * 4) + r;
        const int col = wc + ns * 16 + (lane & 15);
        out[((size_t)b * SEQ + row) * EMB + col] = acc[ms][ns][r] + ev4[ns];
      }
}

// ---------------------------------------------------------------------------
extern "C" void kernel_launch(void* const* d_in, const int* in_sizes, int n_in,
                              void* d_out, int out_size, void* d_ws, size_t ws_size,
                              hipStream_t stream) {
  (void)in_sizes; (void)n_in; (void)out_size;
  const float* x  = (const float*)d_in[0];
  const float* Wq = (const float*)d_in[1];
  const float* bq = (const float*)d_in[2];
  const float* Wk = (const float*)d_in[3];
  const float* bk = (const float*)d_in[4];
  const float* Wv = (const float*)d_in[5];
  const float* bv = (const float*)d_in[6];
  const float* Wo = (const float*)d_in[7];
  const float* bo = (const float*)d_in[8];
  float* out = (float*)d_out;

  char* ws = (char*)d_ws;
  const size_t MB = (size_t)1 << 20;
  const size_t XBF_BYTES = (size_t)BATCH * SEQ * EMB * 2;       // 128 MiB
  const size_t NEED2 = XBF_BYTES + 98 * MB + 256 * 1024;        // ~226 MiB
  const size_t NEED1 = XBF_BYTES + 66 * MB + 256 * 1024;        // ~194 MiB

  if (ws_size >= NEED2) {
    // xbf | P0,P1 (64M; Cm/Dm reuse after k2a) | A (32M) | attn | svp(2) | ev
    unsigned short* xbf  = (unsigned short*)(ws);
    float*          P    = (float*)(ws + XBF_BYTES);
    unsigned short* Cm   = (unsigned short*)(ws + XBF_BYTES);
    unsigned short* Dm   = (unsigned short*)(ws + XBF_BYTES + 16 * MB);
    float*          A    = (float*)(ws + XBF_BYTES + 64 * MB);
    unsigned short* attn = (unsigned short*)(ws + XBF_BYTES + 96 * MB);
    float*          svp  = (float*)(ws + XBF_BYTES + 98 * MB);
    float*          ev   = (float*)(ws + XBF_BYTES + 98 * MB + 192 * 1024);

    hipLaunchKernelGGL((k1_gram<2, true>), dim3(BATCH * 8),  dim3(1024), 0, stream, x, P, svp, xbf);
    hipLaunchKernelGGL((k2a_wqg<true>),    dim3(BATCH * 16), dim3(256), 0, stream, Wq, P, A);
    hipLaunchKernelGGL((k2b_logits<2>),    dim3(BATCH * 8),  dim3(256), 0, stream, A, Wq, Wk, bq, bk, svp, attn);
    hipLaunchKernelGGL(k3a_c,              dim3(BATCH * 32), dim3(256), 0, stream, Wo, attn, Cm);
    hipLaunchKernelGGL(k3b_d,              dim3(BATCH * 16), dim3(256), 0, stream, Cm, Wv, bv, bo, Dm, ev);
    hipLaunchKernelGGL((k4_out<true>),     dim3(BATCH * 32), dim3(1024), 0, stream, x, xbf, Dm, ev, out);
  } else if (ws_size >= NEED1) {
    unsigned short* xbf  = (unsigned short*)(ws);
    float*          P    = (float*)(ws + XBF_BYTES);
    unsigned short* Cm   = (unsigned short*)(ws + XBF_BYTES);
    unsigned short* Dm   = (unsigned short*)(ws + XBF_BYTES + 16 * MB);
    float*          A    = (float*)(ws + XBF_BYTES + 32 * MB);
    unsigned short* attn = (unsigned short*)(ws + XBF_BYTES + 64 * MB);
    float*          svp  = (float*)(ws + XBF_BYTES + 66 * MB);
    float*          ev   = (float*)(ws + XBF_BYTES + 66 * MB + 192 * 1024);

    hipLaunchKernelGGL((k1_gram<1, true>), dim3(BATCH * 4),  dim3(1024), 0, stream, x, P, svp, xbf);
    hipLaunchKernelGGL((k2a_wqg<false>),   dim3(BATCH * 16), dim3(256), 0, stream, Wq, P, A);
    hipLaunchKernelGGL((k2b_logits<1>),    dim3(BATCH * 8),  dim3(256), 0, stream, A, Wq, Wk, bq, bk, svp, attn);
    hipLaunchKernelGGL(k3a_c,              dim3(BATCH * 32), dim3(256), 0, stream, Wo, attn, Cm);
    hipLaunchKernelGGL(k3b_d,              dim3(BATCH * 16), dim3(256), 0, stream, Cm, Wv, bv, bo, Dm, ev);
    hipLaunchKernelGGL((k4_out<true>),     dim3(BATCH * 32), dim3(1024), 0, stream, x, xbf, Dm, ev, out);
  } else {
    unsigned short* xbf  = (unsigned short*)(ws);   // unused
    float*          P    = (float*)(ws);
    unsigned short* Cm   = (unsigned short*)(ws);
    unsigned short* Dm   = (unsigned short*)(ws + 16 * MB);
    float*          A    = (float*)(ws + 32 * MB);
    unsigned short* attn = (unsigned short*)(ws + 64 * MB);
    float*          svp  = (float*)(ws + 66 * MB);
    float*          ev   = (float*)(ws + 66 * MB + 192 * 1024);

    hipLaunchKernelGGL((k1_gram<1, false>), dim3(BATCH * 4),  dim3(1024), 0, stream, x, P, svp, xbf);
    hipLaunchKernelGGL((k2a_wqg<false>),    dim3(BATCH * 16), dim3(256), 0, stream, Wq, P, A);
    hipLaunchKernelGGL((k2b_logits<1>),     dim3(BATCH * 8),  dim3(256), 0, stream, A, Wq, Wk, bq, bk, svp, attn);
    hipLaunchKernelGGL(k3a_c,               dim3(BATCH * 32), dim3(256), 0, stream, Wo, attn, Cm);
    hipLaunchKernelGGL(k3b_d,               dim3(BATCH * 16), dim3(256), 0, stream, Cm, Wv, bv, bo, Dm, ev);
    hipLaunchKernelGGL((k4_out<false>),     dim3(BATCH * 32), dim3(1024), 0, stream, x, xbf, Dm, ev, out);
  }
}